// Round 1
// baseline (1007.379 us; speedup 1.0000x reference)
//
#include <hip/hip_runtime.h>
#include <hip/hip_bf16.h>

typedef __hip_bfloat16 bf16;
typedef __attribute__((ext_vector_type(8))) short short8;
typedef __attribute__((ext_vector_type(4))) float f32x4;

// ---------- helpers ----------
static __device__ __forceinline__ float bfbits2f(short s) {
    return __uint_as_float(((unsigned int)(unsigned short)s) << 16);
}
static __device__ __forceinline__ float bf2f(bf16 v) { return __bfloat162float(v); }
static __device__ __forceinline__ bf16 f2bf(float v) { return __float2bfloat16(v); }
static __device__ __forceinline__ short f2bfbits(float f) {
    bf16 h = __float2bfloat16(f);
    return *reinterpret_cast<short*>(&h);
}

// ======================================================================
// fp32 -> bf16 conversion kernels
// ======================================================================
__launch_bounds__(256)
__global__ void cvt_xy_kernel(const float* __restrict__ x, const float* __restrict__ y,
                              bf16* __restrict__ xb, bf16* __restrict__ yb)
{
    int t = blockIdx.x * 256 + threadIdx.x;       // 2,097,152 threads total
    int which = t >> 20;                          // 1,048,576 threads per tensor (8 elems each)
    size_t i = (size_t)(t & 1048575) * 8;
    const float4* s = (const float4*)((which ? y : x) + i);
    float4 a = s[0], b = s[1];
    short8 p;
    p[0] = f2bfbits(a.x); p[1] = f2bfbits(a.y); p[2] = f2bfbits(a.z); p[3] = f2bfbits(a.w);
    p[4] = f2bfbits(b.x); p[5] = f2bfbits(b.y); p[6] = f2bfbits(b.z); p[7] = f2bfbits(b.w);
    *(short8*)((which ? yb : xb) + i) = p;
}

struct WTab {
    const float* src[10];
    bf16* dst[10];
    int nblk[10];   // blocks per array; each block converts 1024 elems
};

__launch_bounds__(256)
__global__ void cvt_w_kernel(WTab tab)
{
    int b = blockIdx.x;
    int a = 0, base = 0;
    while (a < 9 && b >= base + tab.nblk[a]) { base += tab.nblk[a]; ++a; }
    int lb = b - base;
    size_t i = ((size_t)lb * 256 + threadIdx.x) * 4;
    const float4 v = *(const float4*)(tab.src[a] + i);
    bf16* d = tab.dst[a] + i;
    d[0] = f2bf(v.x); d[1] = f2bf(v.y); d[2] = f2bf(v.z); d[3] = f2bf(v.w);
}

// ======================================================================
// bf16 MFMA GEMM:  out[M=32768, N=256] = A(M x KT) @ W(256 x KT)^T
// A tensors always have 256 cols; CONCAT: K=512 split across A0|A1.
// 128x128 tile, BK=32, 4 waves (2x2), 16x16x32 MFMA, double-buffered LDS,
// global_load_lds(16B) with XOR-preswizzled source (2-way bank conflicts).
// ======================================================================
static __device__ __forceinline__ void stage_tile(const bf16* __restrict__ g, int ldk,
                                                  char* lds_base, int tid, long m0, int k0)
{
    int wid = tid >> 6;
#pragma unroll
    for (int r = 0; r < 2; ++r) {
        int row = r * 64 + (tid >> 2);               // tile row 0..127
        int q = (tid & 3) * 16;                      // byte-in-row 0..48
        int srcq = q ^ (((row >> 1) & 3) << 4);      // inverse swizzle on the SOURCE
        const char* gsrc = (const char*)(g + (size_t)(m0 + row) * ldk + k0) + srcq;
        char* ldst = lds_base + r * 4096 + (wid << 10);   // wave-uniform; HW adds lane*16
        __builtin_amdgcn_global_load_lds(
            (const __attribute__((address_space(1))) unsigned int*)gsrc,
            (__attribute__((address_space(3))) unsigned int*)ldst, 16, 0, 0);
    }
}

template<int KT, bool CONCAT, bool BIAS, bool LRELU, bool OUT_BF16, bool PERB>
__launch_bounds__(256)
__global__ void gemm_kernel(const bf16* __restrict__ A0, const bf16* __restrict__ A1,
                            const bf16* __restrict__ Bw, const float* __restrict__ bias,
                            bf16* __restrict__ outb, float* __restrict__ outf)
{
    constexpr int NT = KT / 32;
    __shared__ __align__(16) char lds[2 * 16384];   // [buf][A 8KB | B 8KB]
    int tid = threadIdx.x;
    int lane = tid & 63, wid = tid >> 6;
    int wr = wid >> 1, wc = wid & 1;
    long m0 = (long)blockIdx.y * 128;
    int n0 = blockIdx.x * 128;
    const bf16* Bp = Bw;
    if (PERB && m0 >= 16384) Bp += 256 * 256;

    f32x4 acc[4][4];
#pragma unroll
    for (int i = 0; i < 4; ++i)
#pragma unroll
        for (int j = 0; j < 4; ++j) acc[i][j] = (f32x4){0.f, 0.f, 0.f, 0.f};

    // prologue: stage kt=0 into buf 0
    stage_tile(A0, 256, lds, tid, m0, 0);
    stage_tile(Bp, KT, lds + 8192, tid, n0, 0);

    // precomputed swizzled LDS byte offsets for fragment reads
    int kb = (lane >> 4) * 16;
    int offa[4], offb[4];
#pragma unroll
    for (int mi = 0; mi < 4; ++mi) {
        int row = wr * 64 + mi * 16 + (lane & 15);
        offa[mi] = row * 64 + (kb ^ (((row >> 1) & 3) << 4));
    }
#pragma unroll
    for (int ni = 0; ni < 4; ++ni) {
        int row = wc * 64 + ni * 16 + (lane & 15);
        offb[ni] = row * 64 + (kb ^ (((row >> 1) & 3) << 4));
    }

    for (int kt = 0; kt < NT; ++kt) {
        __syncthreads();                 // drains vmcnt: tile kt ready; guards buffer reuse
        int cur = kt & 1;
        if (kt + 1 < NT) {
            int k0 = (kt + 1) * 32;
            const bf16* Asrc = A0; int kk = k0;
            if (CONCAT && k0 >= 256) { Asrc = A1; kk = k0 - 256; }
            char* nb = lds + (cur ^ 1) * 16384;
            stage_tile(Asrc, 256, nb, tid, m0, kk);
            stage_tile(Bp, KT, nb + 8192, tid, n0, k0);
        }
        const char* As = lds + cur * 16384;
        const char* Bs = As + 8192;
        short8 af[4], bfr[4];
#pragma unroll
        for (int mi = 0; mi < 4; ++mi) af[mi] = *(const short8*)(As + offa[mi]);
#pragma unroll
        for (int ni = 0; ni < 4; ++ni) bfr[ni] = *(const short8*)(Bs + offb[ni]);
#pragma unroll
        for (int mi = 0; mi < 4; ++mi)
#pragma unroll
            for (int ni = 0; ni < 4; ++ni)
                acc[mi][ni] = __builtin_amdgcn_mfma_f32_16x16x32_bf16(af[mi], bfr[ni], acc[mi][ni], 0, 0, 0);
    }

    // epilogue: C/D layout col=lane&15, row=(lane>>4)*4+j  [HW-verified]
    float bv[4];
#pragma unroll
    for (int ni = 0; ni < 4; ++ni)
        bv[ni] = BIAS ? bias[n0 + wc * 64 + ni * 16 + (lane & 15)] : 0.0f;
    long r0 = m0 + wr * 64;
    int c0 = n0 + wc * 64;
#pragma unroll
    for (int mi = 0; mi < 4; ++mi)
#pragma unroll
        for (int ni = 0; ni < 4; ++ni) {
            int col = c0 + ni * 16 + (lane & 15);
#pragma unroll
            for (int j = 0; j < 4; ++j) {
                size_t row = (size_t)(r0 + mi * 16 + (lane >> 4) * 4 + j);
                float v = acc[mi][ni][j] + bv[ni];
                if (LRELU) v = v > 0.f ? v : 0.01f * v;
                if (OUT_BF16) outb[row * 256 + col] = f2bf(v);
                else          outf[row * 256 + col] = v;
            }
        }
}

// ======================================================================
// per-channel squared L2 norms over n (for q_x, k_x, q_y, k_y)
// norm2 layout: [tensor(qx,kx,qy,ky)][b][c]
// ======================================================================
__launch_bounds__(256)
__global__ void norm2_kernel(const bf16* __restrict__ qx, const bf16* __restrict__ kx,
                             const bf16* __restrict__ qy, const bf16* __restrict__ ky,
                             float* __restrict__ norm2)
{
    int bid = blockIdx.x;                 // t*128 + b*64 + s, grid 512
    int s = bid & 63, b = (bid >> 6) & 1, t = bid >> 7;
    const bf16* T = t == 0 ? qx : t == 1 ? kx : t == 2 ? qy : ky;
    int c = threadIdx.x;
    const bf16* p = T + ((size_t)b * 16384 + (size_t)s * 256) * 256 + c;
    float acc = 0.f;
    for (int r = 0; r < 256; ++r) {
        float v = bf2f(p[(size_t)r * 256]);
        acc += v * v;
    }
    atomicAdd(&norm2[(t * 2 + b) * 256 + c], acc);
}

// ======================================================================
// per-head Gram matrices: gram[pair][b][h][d][e] = sum_n K[n,h*32+d]*Q[n,h*32+e]
// pair0: K=ky,Q=qx (attn_x); pair1: K=kx,Q=qy (attn_y)
// ======================================================================
__launch_bounds__(256)
__global__ void gram_kernel(const bf16* __restrict__ qx, const bf16* __restrict__ kx,
                            const bf16* __restrict__ qy, const bf16* __restrict__ ky,
                            float* __restrict__ gram)
{
    int bid = blockIdx.x;                 // pair*256 + b*128 + h*16 + s, grid 512
    int s = bid & 15, h = (bid >> 4) & 7, b = (bid >> 7) & 1, pair = bid >> 8;
    const bf16* K = pair ? kx : ky;
    const bf16* Q = pair ? qy : qx;
    __shared__ __align__(16) bf16 Ks[256][32];
    __shared__ __align__(16) bf16 Qs[256][32];
    int tid = threadIdx.x;
    int d = tid >> 3, e0 = (tid & 7) * 4;
    float a0 = 0.f, a1 = 0.f, a2 = 0.f, a3 = 0.f;
    size_t rowbase = (size_t)b * 16384 + (size_t)s * 1024;
    int cbase = h * 32;
    for (int ch = 0; ch < 4; ++ch) {
        __syncthreads();
#pragma unroll
        for (int i = 0; i < 4; ++i) {
            int idx = i * 256 + tid;       // 0..1023
            int row = idx >> 2;
            int part = idx & 3;
            size_t gofs = (rowbase + (size_t)ch * 256 + row) * 256 + cbase + part * 8;
            *(short8*)(&Ks[row][part * 8]) = *(const short8*)(K + gofs);
            *(short8*)(&Qs[row][part * 8]) = *(const short8*)(Q + gofs);
        }
        __syncthreads();
        for (int r = 0; r < 256; ++r) {
            float kd = bf2f(Ks[r][d]);
            a0 += kd * bf2f(Qs[r][e0 + 0]);
            a1 += kd * bf2f(Qs[r][e0 + 1]);
            a2 += kd * bf2f(Qs[r][e0 + 2]);
            a3 += kd * bf2f(Qs[r][e0 + 3]);
        }
    }
    float* gp = gram + ((size_t)((pair * 2 + b) * 8 + h)) * 1024 + d * 32 + e0;
    atomicAdd(gp + 0, a0); atomicAdd(gp + 1, a1);
    atomicAdd(gp + 2, a2); atomicAdd(gp + 3, a3);
}

// ======================================================================
// softmax over e + fold attention into project-out weights:
// PW[pair][b][o][h*32+e] = sum_d pw[o][h*32+d] * attn[pair][b][h][d][e]
// ======================================================================
__launch_bounds__(256)
__global__ void attn_pw_kernel(const float* __restrict__ gram, const float* __restrict__ norm2,
                               const float* __restrict__ rsx, const float* __restrict__ rsy,
                               const float* __restrict__ pxw, const float* __restrict__ pyw,
                               bf16* __restrict__ PW)
{
    int bid = blockIdx.x;                 // pair*16 + b*8 + h, grid 32
    int h = bid & 7, b = (bid >> 3) & 1, pair = bid >> 4;
    const float* G = gram + ((size_t)((pair * 2 + b) * 8 + h)) * 1024;
    int tK = pair ? 1 : 3;                // kx : ky
    int tQ = pair ? 2 : 0;                // qy : qx
    const float* nk2 = norm2 + (tK * 2 + b) * 256 + h * 32;
    const float* nq2 = norm2 + (tQ * 2 + b) * 256 + h * 32;
    float rs = (pair ? rsy : rsx)[h];
    __shared__ float attn[32][32];
    int t = threadIdx.x;
    if (t < 32) {
        int d = t;
        float nk = fmaxf(sqrtf(nk2[d]), 1e-12f);
        float row[32];
        float mx = -3.4e38f;
#pragma unroll
        for (int e = 0; e < 32; ++e) {
            float nq = fmaxf(sqrtf(nq2[e]), 1e-12f);
            float L = G[d * 32 + e] / (nk * nq) * rs;
            row[e] = L;
            mx = fmaxf(mx, L);
        }
        float sum = 0.f;
#pragma unroll
        for (int e = 0; e < 32; ++e) { row[e] = expf(row[e] - mx); sum += row[e]; }
        float inv = 1.0f / sum;
#pragma unroll
        for (int e = 0; e < 32; ++e) attn[d][e] = row[e] * inv;
    }
    __syncthreads();
    const float* pw = pair ? pyw : pxw;
    int o = t;
    float wrow[32];
#pragma unroll
    for (int d2 = 0; d2 < 32; ++d2) wrow[d2] = pw[o * 256 + h * 32 + d2];
    bf16* dst = PW + ((size_t)(pair * 2 + b) * 256 + o) * 256 + h * 32;
#pragma unroll
    for (int e = 0; e < 32; ++e) {
        float sv = 0.f;
#pragma unroll
        for (int d2 = 0; d2 < 32; ++d2) sv += wrow[d2] * attn[d2][e];
        dst[e] = f2bf(sv);
    }
}

// ======================================================================
// depthwise 3x3 conv, NHWC (2,128,128,256), zero pad.
// GELU_OUT_BF: +exact GELU, write bf16.  else: ADD into fp32 out.
// ======================================================================
template<bool GELU_OUT_BF>
__launch_bounds__(256)
__global__ void dwconv_kernel(const bf16* __restrict__ in, const float* __restrict__ w,
                              const float* __restrict__ bias, bf16* __restrict__ outb,
                              float* __restrict__ outf)
{
    int t = blockIdx.x * 256 + threadIdx.x;   // 1,048,576 threads
    int cg = t & 31;
    int pix = t >> 5;
    int x = pix & 127, y = (pix >> 7) & 127, b = pix >> 14;
    int c0 = cg * 8;
    float acc[8];
#pragma unroll
    for (int j = 0; j < 8; ++j) acc[j] = bias[c0 + j];
#pragma unroll
    for (int ky = -1; ky <= 1; ++ky) {
        int yy = y + ky;
        if (yy < 0 || yy > 127) continue;
#pragma unroll
        for (int kx = -1; kx <= 1; ++kx) {
            int xx = x + kx;
            if (xx < 0 || xx > 127) continue;
            const short8 v = *(const short8*)(in + (((size_t)(b << 14) + (yy << 7) + xx) << 8) + c0);
#pragma unroll
            for (int j = 0; j < 8; ++j)
                acc[j] += w[(c0 + j) * 9 + (ky + 1) * 3 + (kx + 1)] * bfbits2f(v[j]);
        }
    }
    size_t base = ((size_t)pix << 8) + c0;
    if (GELU_OUT_BF) {
#pragma unroll
        for (int j = 0; j < 8; ++j) {
            float a = acc[j];
            a = 0.5f * a * (1.0f + erff(a * 0.70710678118654752f));
            outb[base + j] = f2bf(a);
        }
    } else {
        float4* o = (float4*)(outf + base);
        float4 o0 = o[0], o1 = o[1];
        o0.x += acc[0]; o0.y += acc[1]; o0.z += acc[2]; o0.w += acc[3];
        o1.x += acc[4]; o1.y += acc[5]; o1.z += acc[6]; o1.w += acc[7];
        o[0] = o0; o[1] = o1;
    }
}

// ======================================================================
// launch
// ======================================================================
extern "C" void kernel_launch(void* const* d_in, const int* in_sizes, int n_in,
                              void* d_out, int out_size, void* d_ws, size_t ws_size,
                              hipStream_t stream)
{
    const float* x_in  = (const float*)d_in[0];
    const float* y_in  = (const float*)d_in[1];
    const float* fx_w1 = (const float*)d_in[2];
    const float* fx_b1 = (const float*)d_in[3];
    const float* fx_w2 = (const float*)d_in[4];
    const float* fx_b2 = (const float*)d_in[5];
    const float* fy_w1 = (const float*)d_in[6];
    const float* fy_b1 = (const float*)d_in[7];
    const float* fy_w2 = (const float*)d_in[8];
    const float* fy_b2 = (const float*)d_in[9];
    const float* q_w1  = (const float*)d_in[10];
    const float* q_b1  = (const float*)d_in[11];
    const float* q_w2  = (const float*)d_in[12];
    const float* k_w1  = (const float*)d_in[13];
    const float* k_b1  = (const float*)d_in[14];
    const float* k_w2  = (const float*)d_in[15];
    const float* v_w1  = (const float*)d_in[16];
    const float* v_b1  = (const float*)d_in[17];
    const float* v_w2  = (const float*)d_in[18];
    const float* rescale_x = (const float*)d_in[19];
    const float* rescale_y = (const float*)d_in[20];
    const float* px_w  = (const float*)d_in[21];
    const float* px_b  = (const float*)d_in[22];
    const float* py_w  = (const float*)d_in[23];
    const float* py_b  = (const float*)d_in[24];
    const float* pe_w1 = (const float*)d_in[25];
    const float* pe_b1 = (const float*)d_in[26];
    const float* pe_w2 = (const float*)d_in[27];
    const float* pe_b2 = (const float*)d_in[28];

    char* ws = (char*)d_ws;
    const size_t NB = 16777216;   // one (32768 x 256) bf16 activation buffer
    bf16* xbf  = (bf16*)(ws + 0 * NB);
    bf16* ybf  = (bf16*)(ws + 1 * NB);
    bf16* hbuf = (bf16*)(ws + 2 * NB);   // shared hidden / conv temp
    bf16* fkx  = (bf16*)(ws + 3 * NB);
    bf16* fky  = (bf16*)(ws + 4 * NB);
    bf16* qx   = (bf16*)(ws + 5 * NB);
    bf16* kx   = (bf16*)(ws + 6 * NB);
    bf16* vx   = (bf16*)(ws + 7 * NB);
    bf16* qy   = (bf16*)(ws + 8 * NB);
    bf16* ky   = (bf16*)(ws + 9 * NB);
    bf16* vy   = (bf16*)(ws + 10 * NB);
    char* wreg = ws + 11 * NB;
    bf16* w_fx1 = (bf16*)(wreg + 0);
    bf16* w_fx2 = (bf16*)(wreg + 262144);
    bf16* w_fy1 = (bf16*)(wreg + 393216);
    bf16* w_fy2 = (bf16*)(wreg + 655360);
    bf16* w_q1  = (bf16*)(wreg + 786432);
    bf16* w_q2  = (bf16*)(wreg + 917504);
    bf16* w_k1  = (bf16*)(wreg + 1048576);
    bf16* w_k2  = (bf16*)(wreg + 1179648);
    bf16* w_v1  = (bf16*)(wreg + 1310720);
    bf16* w_v2  = (bf16*)(wreg + 1441792);
    float* gram  = (float*)(wreg + 1572864);             // 2*2*8*1024 f32 = 128 KB
    float* norm2 = (float*)(wreg + 1572864 + 131072);    // 4*2*256 f32 = 8 KB
    bf16* PW    = (bf16*)(wreg + 1572864 + 139264);      // 4*256*256 bf16 = 512 KB

    float* outx = (float*)d_out;
    float* outy = outx + 8388608;

    // zero the accumulators (ws is poisoned 0xAA before every call)
    hipMemsetAsync(gram, 0, 131072 + 8192, stream);

    // casts
    cvt_xy_kernel<<<8192, 256, 0, stream>>>(x_in, y_in, xbf, ybf);
    WTab tab;
    const float* ws_src[10] = {fx_w1, fx_w2, fy_w1, fy_w2, q_w1, q_w2, k_w1, k_w2, v_w1, v_w2};
    bf16* ws_dst[10] = {w_fx1, w_fx2, w_fy1, w_fy2, w_q1, w_q2, w_k1, w_k2, w_v1, w_v2};
    int nblk[10] = {128, 64, 128, 64, 64, 64, 64, 64, 64, 64};
    for (int i = 0; i < 10; ++i) { tab.src[i] = ws_src[i]; tab.dst[i] = ws_dst[i]; tab.nblk[i] = nblk[i]; }
    cvt_w_kernel<<<768, 256, 0, stream>>>(tab);

    dim3 gg(2, 256);
    // fusion_x / fusion_y  (A = [x|y] concat, K=512)
    gemm_kernel<512, true,  true,  true,  true,  false><<<gg, 256, 0, stream>>>(xbf, ybf, w_fx1, fx_b1, hbuf, nullptr);
    gemm_kernel<256, false, true,  false, true,  false><<<gg, 256, 0, stream>>>(hbuf, nullptr, w_fx2, fx_b2, fkx, nullptr);
    gemm_kernel<512, true,  true,  true,  true,  false><<<gg, 256, 0, stream>>>(xbf, ybf, w_fy1, fy_b1, hbuf, nullptr);
    gemm_kernel<256, false, true,  false, true,  false><<<gg, 256, 0, stream>>>(hbuf, nullptr, w_fy2, fy_b2, fky, nullptr);
    // q/k/v MLPs (shared weights for x and y)
    gemm_kernel<256, false, true,  true,  true,  false><<<gg, 256, 0, stream>>>(xbf, nullptr, w_q1, q_b1, hbuf, nullptr);
    gemm_kernel<256, false, false, false, true,  false><<<gg, 256, 0, stream>>>(hbuf, nullptr, w_q2, nullptr, qx, nullptr);
    gemm_kernel<256, false, true,  true,  true,  false><<<gg, 256, 0, stream>>>(fkx, nullptr, w_k1, k_b1, hbuf, nullptr);
    gemm_kernel<256, false, false, false, true,  false><<<gg, 256, 0, stream>>>(hbuf, nullptr, w_k2, nullptr, kx, nullptr);
    gemm_kernel<256, false, true,  true,  true,  false><<<gg, 256, 0, stream>>>(xbf, nullptr, w_v1, v_b1, hbuf, nullptr);
    gemm_kernel<256, false, false, false, true,  false><<<gg, 256, 0, stream>>>(hbuf, nullptr, w_v2, nullptr, vx, nullptr);
    gemm_kernel<256, false, true,  true,  true,  false><<<gg, 256, 0, stream>>>(ybf, nullptr, w_q1, q_b1, hbuf, nullptr);
    gemm_kernel<256, false, false, false, true,  false><<<gg, 256, 0, stream>>>(hbuf, nullptr, w_q2, nullptr, qy, nullptr);
    gemm_kernel<256, false, true,  true,  true,  false><<<gg, 256, 0, stream>>>(fky, nullptr, w_k1, k_b1, hbuf, nullptr);
    gemm_kernel<256, false, false, false, true,  false><<<gg, 256, 0, stream>>>(hbuf, nullptr, w_k2, nullptr, ky, nullptr);
    gemm_kernel<256, false, true,  true,  true,  false><<<gg, 256, 0, stream>>>(ybf, nullptr, w_v1, v_b1, hbuf, nullptr);
    gemm_kernel<256, false, false, false, true,  false><<<gg, 256, 0, stream>>>(hbuf, nullptr, w_v2, nullptr, vy, nullptr);

    // attention statistics
    norm2_kernel<<<512, 256, 0, stream>>>(qx, kx, qy, ky, norm2);
    gram_kernel<<<512, 256, 0, stream>>>(qx, kx, qy, ky, gram);
    attn_pw_kernel<<<32, 256, 0, stream>>>(gram, norm2, rescale_x, rescale_y, px_w, py_w, PW);

    // project-out GEMMs (per-batch folded attention matrix) -> fp32 out
    gemm_kernel<256, false, true, false, false, true><<<gg, 256, 0, stream>>>(vx, nullptr, PW, px_b, nullptr, outx);
    gemm_kernel<256, false, true, false, false, true><<<gg, 256, 0, stream>>>(vy, nullptr, PW + 2 * 65536, py_b, nullptr, outy);

    // pos_emb chains: conv1+GELU -> hbuf(bf16), conv2 adds into out
    dwconv_kernel<true ><<<4096, 256, 0, stream>>>(vx, pe_w1, pe_b1, hbuf, nullptr);
    dwconv_kernel<false><<<4096, 256, 0, stream>>>(hbuf, pe_w2, pe_b2, nullptr, outx);
    dwconv_kernel<true ><<<4096, 256, 0, stream>>>(vy, pe_w1, pe_b1, hbuf, nullptr);
    dwconv_kernel<false><<<4096, 256, 0, stream>>>(hbuf, pe_w2, pe_b2, nullptr, outy);
}

// Round 2
// 512.468 us; speedup vs baseline: 1.9657x; 1.9657x over previous
//
#include <hip/hip_runtime.h>
#include <hip/hip_bf16.h>

typedef __hip_bfloat16 bf16;
typedef __attribute__((ext_vector_type(8))) short short8;
typedef __attribute__((ext_vector_type(4))) float f32x4;

// ---------- helpers ----------
static __device__ __forceinline__ float bfbits2f(short s) {
    return __uint_as_float(((unsigned int)(unsigned short)s) << 16);
}
static __device__ __forceinline__ float bf2f(bf16 v) { return __bfloat162float(v); }
static __device__ __forceinline__ bf16 f2bf(float v) { return __float2bfloat16(v); }
static __device__ __forceinline__ short f2bfbits(float f) {
    bf16 h = __float2bfloat16(f);
    return *reinterpret_cast<short*>(&h);
}

// ======================================================================
// fp32 -> bf16 conversion kernels
// ======================================================================
__launch_bounds__(256)
__global__ void cvt_xy_kernel(const float* __restrict__ x, const float* __restrict__ y,
                              bf16* __restrict__ xb, bf16* __restrict__ yb)
{
    int t = blockIdx.x * 256 + threadIdx.x;
    int which = t >> 20;
    size_t i = (size_t)(t & 1048575) * 8;
    const float4* s = (const float4*)((which ? y : x) + i);
    float4 a = s[0], b = s[1];
    short8 p;
    p[0] = f2bfbits(a.x); p[1] = f2bfbits(a.y); p[2] = f2bfbits(a.z); p[3] = f2bfbits(a.w);
    p[4] = f2bfbits(b.x); p[5] = f2bfbits(b.y); p[6] = f2bfbits(b.z); p[7] = f2bfbits(b.w);
    *(short8*)((which ? yb : xb) + i) = p;
}

struct WTab {
    const float* src[10];
    bf16* dst[10];
    int nblk[10];
};

__launch_bounds__(256)
__global__ void cvt_w_kernel(WTab tab)
{
    int b = blockIdx.x;
    int a = 0, base = 0;
    while (a < 9 && b >= base + tab.nblk[a]) { base += tab.nblk[a]; ++a; }
    int lb = b - base;
    size_t i = ((size_t)lb * 256 + threadIdx.x) * 4;
    const float4 v = *(const float4*)(tab.src[a] + i);
    bf16* d = tab.dst[a] + i;
    d[0] = f2bf(v.x); d[1] = f2bf(v.y); d[2] = f2bf(v.z); d[3] = f2bf(v.w);
}

// transpose PE dwconv weights (C,1,3,3) -> [tap][channel] fp32 (coalesced reads)
__launch_bounds__(256)
__global__ void cvt_pe_kernel(const float* __restrict__ w1, const float* __restrict__ w2,
                              float* __restrict__ t1, float* __restrict__ t2)
{
    int t = blockIdx.x * 256 + threadIdx.x;     // 2*2304 = 4608
    if (t >= 4608) return;
    int which = t >= 2304;
    int i = which ? t - 2304 : t;
    int c = i / 9, k = i % 9;
    (which ? t2 : t1)[k * 256 + c] = (which ? w2 : w1)[i];
}

// ======================================================================
// bf16 MFMA GEMM:  out[M, 256] = A(M x KT) @ W(256 x KT)^T
// MODE 0: single B/bias.  MODE 1: B += (row/16384)*65536 bf16; bias2 for
// rows >= 32768 (merged x/y project-out with per-(pair,batch) PW).
// NORM2: accumulate per-column sum of squares into nrm[(row/16384)*256+col].
// ======================================================================
static __device__ __forceinline__ void stage_tile(const bf16* __restrict__ g, int ldk,
                                                  char* lds_base, int tid, long m0, int k0)
{
    int wid = tid >> 6;
#pragma unroll
    for (int r = 0; r < 2; ++r) {
        int row = r * 64 + (tid >> 2);
        int q = (tid & 3) * 16;
        int srcq = q ^ (((row >> 1) & 3) << 4);
        const char* gsrc = (const char*)(g + (size_t)(m0 + row) * ldk + k0) + srcq;
        char* ldst = lds_base + r * 4096 + (wid << 10);
        __builtin_amdgcn_global_load_lds(
            (const __attribute__((address_space(1))) unsigned int*)gsrc,
            (__attribute__((address_space(3))) unsigned int*)ldst, 16, 0, 0);
    }
}

template<int KT, bool CONCAT, bool BIAS, bool LRELU, bool OUT_BF16, int MODE, bool NORM2>
__launch_bounds__(256)
__global__ void gemm_kernel(const bf16* __restrict__ A0, const bf16* __restrict__ A1,
                            const bf16* __restrict__ Bw,
                            const float* __restrict__ bias, const float* __restrict__ bias2,
                            bf16* __restrict__ outb, float* __restrict__ outf,
                            float* __restrict__ nrm)
{
    constexpr int NT = KT / 32;
    __shared__ __align__(16) char lds[2 * 16384];
    int tid = threadIdx.x;
    int lane = tid & 63, wid = tid >> 6;
    int wr = wid >> 1, wc = wid & 1;
    long m0 = (long)blockIdx.y * 128;
    int n0 = blockIdx.x * 128;
    const bf16* Bp = Bw;
    if (MODE == 1) Bp += (size_t)(m0 >> 14) * 65536;
    const float* bsel = (MODE == 1 && m0 >= 32768) ? bias2 : bias;

    f32x4 acc[4][4];
#pragma unroll
    for (int i = 0; i < 4; ++i)
#pragma unroll
        for (int j = 0; j < 4; ++j) acc[i][j] = (f32x4){0.f, 0.f, 0.f, 0.f};

    stage_tile(A0, 256, lds, tid, m0, 0);
    stage_tile(Bp, KT, lds + 8192, tid, n0, 0);

    int kb = (lane >> 4) * 16;
    int offa[4], offb[4];
#pragma unroll
    for (int mi = 0; mi < 4; ++mi) {
        int row = wr * 64 + mi * 16 + (lane & 15);
        offa[mi] = row * 64 + (kb ^ (((row >> 1) & 3) << 4));
    }
#pragma unroll
    for (int ni = 0; ni < 4; ++ni) {
        int row = wc * 64 + ni * 16 + (lane & 15);
        offb[ni] = row * 64 + (kb ^ (((row >> 1) & 3) << 4));
    }

    for (int kt = 0; kt < NT; ++kt) {
        __syncthreads();
        int cur = kt & 1;
        if (kt + 1 < NT) {
            int k0 = (kt + 1) * 32;
            const bf16* Asrc = A0; int kk = k0;
            if (CONCAT && k0 >= 256) { Asrc = A1; kk = k0 - 256; }
            char* nb = lds + (cur ^ 1) * 16384;
            stage_tile(Asrc, 256, nb, tid, m0, kk);
            stage_tile(Bp, KT, nb + 8192, tid, n0, k0);
        }
        const char* As = lds + cur * 16384;
        const char* Bs = As + 8192;
        short8 af[4], bfr[4];
#pragma unroll
        for (int mi = 0; mi < 4; ++mi) af[mi] = *(const short8*)(As + offa[mi]);
#pragma unroll
        for (int ni = 0; ni < 4; ++ni) bfr[ni] = *(const short8*)(Bs + offb[ni]);
#pragma unroll
        for (int mi = 0; mi < 4; ++mi)
#pragma unroll
            for (int ni = 0; ni < 4; ++ni)
                acc[mi][ni] = __builtin_amdgcn_mfma_f32_16x16x32_bf16(af[mi], bfr[ni], acc[mi][ni], 0, 0, 0);
    }

    // epilogue: C/D layout col=lane&15, row=(lane>>4)*4+j
    float bv[4];
#pragma unroll
    for (int ni = 0; ni < 4; ++ni)
        bv[ni] = BIAS ? bsel[n0 + wc * 64 + ni * 16 + (lane & 15)] : 0.0f;
    float vsq[4] = {0.f, 0.f, 0.f, 0.f};
    long r0 = m0 + wr * 64;
    int c0 = n0 + wc * 64;
#pragma unroll
    for (int mi = 0; mi < 4; ++mi)
#pragma unroll
        for (int ni = 0; ni < 4; ++ni) {
            int col = c0 + ni * 16 + (lane & 15);
#pragma unroll
            for (int j = 0; j < 4; ++j) {
                size_t row = (size_t)(r0 + mi * 16 + (lane >> 4) * 4 + j);
                float v = acc[mi][ni][j] + bv[ni];
                if (LRELU) v = v > 0.f ? v : 0.01f * v;
                if (NORM2) vsq[ni] += v * v;
                if (OUT_BF16) outb[row * 256 + col] = f2bf(v);
                else          outf[row * 256 + col] = v;
            }
        }
    if (NORM2) {
        __syncthreads();
        float* cs = (float*)lds;
        if (tid < 128) cs[tid] = 0.f;
        __syncthreads();
#pragma unroll
        for (int ni = 0; ni < 4; ++ni)
            atomicAdd(&cs[wc * 64 + ni * 16 + (lane & 15)], vsq[ni]);
        __syncthreads();
        if (tid < 128)
            atomicAdd(nrm + (int)(m0 >> 14) * 256 + n0 + tid, cs[tid]);
    }
}

// ======================================================================
// per-head Gram matrices: gram[pair][b][h][d][e] = sum_n K[n,h*32+d]*Q[n,h*32+e]
// ======================================================================
__launch_bounds__(256)
__global__ void gram_kernel(const bf16* __restrict__ qx, const bf16* __restrict__ kx,
                            const bf16* __restrict__ qy, const bf16* __restrict__ ky,
                            float* __restrict__ gram)
{
    int bid = blockIdx.x;                 // pair*256 + b*128 + h*16 + s
    int s = bid & 15, h = (bid >> 4) & 7, b = (bid >> 7) & 1, pair = bid >> 8;
    const bf16* K = pair ? kx : ky;
    const bf16* Q = pair ? qy : qx;
    __shared__ __align__(16) bf16 Ks[256][32];
    __shared__ __align__(16) bf16 Qs[256][32];
    int tid = threadIdx.x;
    int d = tid >> 3, e0 = (tid & 7) * 4;
    float a0 = 0.f, a1 = 0.f, a2 = 0.f, a3 = 0.f;
    size_t rowbase = (size_t)b * 16384 + (size_t)s * 1024;
    int cbase = h * 32;
    for (int ch = 0; ch < 4; ++ch) {
        __syncthreads();
#pragma unroll
        for (int i = 0; i < 4; ++i) {
            int idx = i * 256 + tid;
            int row = idx >> 2;
            int part = idx & 3;
            size_t gofs = (rowbase + (size_t)ch * 256 + row) * 256 + cbase + part * 8;
            *(short8*)(&Ks[row][part * 8]) = *(const short8*)(K + gofs);
            *(short8*)(&Qs[row][part * 8]) = *(const short8*)(Q + gofs);
        }
        __syncthreads();
        for (int r = 0; r < 256; ++r) {
            float kd = bf2f(Ks[r][d]);
            a0 += kd * bf2f(Qs[r][e0 + 0]);
            a1 += kd * bf2f(Qs[r][e0 + 1]);
            a2 += kd * bf2f(Qs[r][e0 + 2]);
            a3 += kd * bf2f(Qs[r][e0 + 3]);
        }
    }
    float* gp = gram + ((size_t)((pair * 2 + b) * 8 + h)) * 1024 + d * 32 + e0;
    atomicAdd(gp + 0, a0); atomicAdd(gp + 1, a1);
    atomicAdd(gp + 2, a2); atomicAdd(gp + 3, a3);
}

// ======================================================================
// softmax + fold attention into project-out weights
// norm2 layout: [qx_b0,qx_b1,qy_b0,qy_b1,kx_b0,kx_b1,ky_b0,ky_b1][256]
// ======================================================================
__launch_bounds__(256)
__global__ void attn_pw_kernel(const float* __restrict__ gram, const float* __restrict__ norm2,
                               const float* __restrict__ rsx, const float* __restrict__ rsy,
                               const float* __restrict__ pxw, const float* __restrict__ pyw,
                               bf16* __restrict__ PW)
{
    int bid = blockIdx.x;                 // pair*16 + b*8 + h
    int h = bid & 7, b = (bid >> 3) & 1, pair = bid >> 4;
    const float* G = gram + ((size_t)((pair * 2 + b) * 8 + h)) * 1024;
    const float* nk2 = norm2 + (pair ? (4 + b) : (6 + b)) * 256 + h * 32;
    const float* nq2 = norm2 + (pair ? (2 + b) : (0 + b)) * 256 + h * 32;
    float rs = (pair ? rsy : rsx)[h];
    __shared__ float attn[32][32];
    int t = threadIdx.x;
    if (t < 32) {
        int d = t;
        float nk = fmaxf(sqrtf(nk2[d]), 1e-12f);
        float row[32];
        float mx = -3.4e38f;
#pragma unroll
        for (int e = 0; e < 32; ++e) {
            float nq = fmaxf(sqrtf(nq2[e]), 1e-12f);
            float L = G[d * 32 + e] / (nk * nq) * rs;
            row[e] = L;
            mx = fmaxf(mx, L);
        }
        float sum = 0.f;
#pragma unroll
        for (int e = 0; e < 32; ++e) { row[e] = expf(row[e] - mx); sum += row[e]; }
        float inv = 1.0f / sum;
#pragma unroll
        for (int e = 0; e < 32; ++e) attn[d][e] = row[e] * inv;
    }
    __syncthreads();
    const float* pw = pair ? pyw : pxw;
    int o = t;
    float wrow[32];
#pragma unroll
    for (int d2 = 0; d2 < 32; ++d2) wrow[d2] = pw[o * 256 + h * 32 + d2];
    bf16* dst = PW + ((size_t)(pair * 2 + b) * 256 + o) * 256 + h * 32;
#pragma unroll
    for (int e = 0; e < 32; ++e) {
        float sv = 0.f;
#pragma unroll
        for (int d2 = 0; d2 < 32; ++d2) sv += wrow[d2] * attn[d2][e];
        dst[e] = f2bf(sv);
    }
}

// ======================================================================
// depthwise 3x3 conv, NHWC (2,128,128,256), zero pad.
// wT: transposed weights [tap][channel] fp32. Each thread: 8 channels x
// 4-pixel column (weights loaded once, coalesced). 262144 threads.
// ======================================================================
template<bool GELU_OUT_BF>
__launch_bounds__(256)
__global__ void dwconv_kernel(const bf16* __restrict__ in, const float* __restrict__ wT,
                              const float* __restrict__ bias, bf16* __restrict__ outb,
                              float* __restrict__ outf)
{
    int t = blockIdx.x * 256 + threadIdx.x;   // 1024 blocks
    int cg = t & 31;
    int x = (t >> 5) & 127;
    int chunk = (t >> 12) & 31;
    int b = t >> 17;
    int c0 = cg * 8;

    float w[9][8];
#pragma unroll
    for (int k = 0; k < 9; ++k) {
        float4 a = *(const float4*)(wT + k * 256 + c0);
        float4 bq = *(const float4*)(wT + k * 256 + c0 + 4);
        w[k][0] = a.x; w[k][1] = a.y; w[k][2] = a.z; w[k][3] = a.w;
        w[k][4] = bq.x; w[k][5] = bq.y; w[k][6] = bq.z; w[k][7] = bq.w;
    }
    float bs[8];
    {
        float4 a = *(const float4*)(bias + c0);
        float4 bq = *(const float4*)(bias + c0 + 4);
        bs[0] = a.x; bs[1] = a.y; bs[2] = a.z; bs[3] = a.w;
        bs[4] = bq.x; bs[5] = bq.y; bs[6] = bq.z; bs[7] = bq.w;
    }
    const short8 z = (short8){0, 0, 0, 0, 0, 0, 0, 0};
    bool xm = x > 0, xp = x < 127;
    int y0 = chunk * 4;

    for (int yi = 0; yi < 4; ++yi) {
        int y = y0 + yi;
        float acc[8];
#pragma unroll
        for (int j = 0; j < 8; ++j) acc[j] = bs[j];
#pragma unroll
        for (int ky = -1; ky <= 1; ++ky) {
            int yy = y + ky;
            if (yy < 0 || yy > 127) continue;
            const bf16* rp = in + ((((size_t)b << 14) + (yy << 7) + x) << 8) + c0;
            short8 vm = xm ? *(const short8*)(rp - 256) : z;
            short8 vc = *(const short8*)(rp);
            short8 vp = xp ? *(const short8*)(rp + 256) : z;
            int k0 = (ky + 1) * 3;
#pragma unroll
            for (int j = 0; j < 8; ++j) {
                acc[j] += w[k0 + 0][j] * bfbits2f(vm[j]);
                acc[j] += w[k0 + 1][j] * bfbits2f(vc[j]);
                acc[j] += w[k0 + 2][j] * bfbits2f(vp[j]);
            }
        }
        size_t base = ((((size_t)b << 14) + (y << 7) + x) << 8) + c0;
        if (GELU_OUT_BF) {
            short8 p;
#pragma unroll
            for (int j = 0; j < 8; ++j) {
                float a = acc[j];
                a = 0.5f * a * (1.0f + erff(a * 0.70710678118654752f));
                p[j] = f2bfbits(a);
            }
            *(short8*)(outb + base) = p;
        } else {
            float4* o = (float4*)(outf + base);
            float4 o0 = o[0], o1 = o[1];
            o0.x += acc[0]; o0.y += acc[1]; o0.z += acc[2]; o0.w += acc[3];
            o1.x += acc[4]; o1.y += acc[5]; o1.z += acc[6]; o1.w += acc[7];
            o[0] = o0; o[1] = o1;
        }
    }
}

// ======================================================================
// launch
// ======================================================================
extern "C" void kernel_launch(void* const* d_in, const int* in_sizes, int n_in,
                              void* d_out, int out_size, void* d_ws, size_t ws_size,
                              hipStream_t stream)
{
    const float* x_in  = (const float*)d_in[0];
    const float* y_in  = (const float*)d_in[1];
    const float* fx_w1 = (const float*)d_in[2];
    const float* fx_b1 = (const float*)d_in[3];
    const float* fx_w2 = (const float*)d_in[4];
    const float* fx_b2 = (const float*)d_in[5];
    const float* fy_w1 = (const float*)d_in[6];
    const float* fy_b1 = (const float*)d_in[7];
    const float* fy_w2 = (const float*)d_in[8];
    const float* fy_b2 = (const float*)d_in[9];
    const float* q_w1  = (const float*)d_in[10];
    const float* q_b1  = (const float*)d_in[11];
    const float* q_w2  = (const float*)d_in[12];
    const float* k_w1  = (const float*)d_in[13];
    const float* k_b1  = (const float*)d_in[14];
    const float* k_w2  = (const float*)d_in[15];
    const float* v_w1  = (const float*)d_in[16];
    const float* v_b1  = (const float*)d_in[17];
    const float* v_w2  = (const float*)d_in[18];
    const float* rescale_x = (const float*)d_in[19];
    const float* rescale_y = (const float*)d_in[20];
    const float* px_w  = (const float*)d_in[21];
    const float* px_b  = (const float*)d_in[22];
    const float* py_w  = (const float*)d_in[23];
    const float* py_b  = (const float*)d_in[24];
    const float* pe_w1 = (const float*)d_in[25];
    const float* pe_b1 = (const float*)d_in[26];
    const float* pe_w2 = (const float*)d_in[27];
    const float* pe_b2 = (const float*)d_in[28];

    char* ws = (char*)d_ws;
    const size_t NB = 16777216;   // one (32768 x 256) bf16 buffer
    // slots: 0 xbf, 1 ybf (adjacent: merged-M GEMMs), 2-3 hbuf (65536 rows),
    // 4 fkx->kx, 5 fky->ky, 6 qx, 7 qy, 8 vx, 9 vy, then weight region.
    bf16* xbf  = (bf16*)(ws + 0 * NB);
    bf16* ybf  = (bf16*)(ws + 1 * NB);
    bf16* hbuf = (bf16*)(ws + 2 * NB);   // 2 slots
    bf16* fkx  = (bf16*)(ws + 4 * NB);
    bf16* fky  = (bf16*)(ws + 5 * NB);
    bf16* kx   = (bf16*)(ws + 4 * NB);   // alias over fkx/fky (dead after k stage1)
    bf16* qx   = (bf16*)(ws + 6 * NB);
    bf16* qy   = (bf16*)(ws + 7 * NB);
    bf16* ky   = (bf16*)(ws + 5 * NB);
    bf16* vx   = (bf16*)(ws + 8 * NB);
    bf16* vy   = (bf16*)(ws + 9 * NB);
    char* wreg = ws + 10 * NB;
    bf16* w_fx1 = (bf16*)(wreg + 0);
    bf16* w_fx2 = (bf16*)(wreg + 262144);
    bf16* w_fy1 = (bf16*)(wreg + 393216);
    bf16* w_fy2 = (bf16*)(wreg + 655360);
    bf16* w_q1  = (bf16*)(wreg + 786432);
    bf16* w_q2  = (bf16*)(wreg + 917504);
    bf16* w_k1  = (bf16*)(wreg + 1048576);
    bf16* w_k2  = (bf16*)(wreg + 1179648);
    bf16* w_v1  = (bf16*)(wreg + 1310720);
    bf16* w_v2  = (bf16*)(wreg + 1441792);
    float* gram  = (float*)(wreg + 1572864);             // 128 KB
    float* norm2 = (float*)(wreg + 1572864 + 131072);    // 8*256 f32 = 8 KB
    bf16* PW     = (bf16*)(wreg + 1572864 + 139264);     // 4*256*256 bf16 = 512 KB
    float* peT1  = (float*)(wreg + 1572864 + 139264 + 524288);           // 9*256 f32
    float* peT2  = (float*)(wreg + 1572864 + 139264 + 524288 + 9216);

    float* outx = (float*)d_out;
    float* outy = outx + 8388608;

    hipMemsetAsync(gram, 0, 139264, stream);   // gram + norm2

    cvt_xy_kernel<<<8192, 256, 0, stream>>>(x_in, y_in, xbf, ybf);
    WTab tab;
    const float* ws_src[10] = {fx_w1, fx_w2, fy_w1, fy_w2, q_w1, q_w2, k_w1, k_w2, v_w1, v_w2};
    bf16* ws_dst[10] = {w_fx1, w_fx2, w_fy1, w_fy2, w_q1, w_q2, w_k1, w_k2, w_v1, w_v2};
    int nblk[10] = {128, 64, 128, 64, 64, 64, 64, 64, 64, 64};
    for (int i = 0; i < 10; ++i) { tab.src[i] = ws_src[i]; tab.dst[i] = ws_dst[i]; tab.nblk[i] = nblk[i]; }
    cvt_w_kernel<<<768, 256, 0, stream>>>(tab);
    cvt_pe_kernel<<<18, 256, 0, stream>>>(pe_w1, pe_w2, peT1, peT2);

    dim3 gg(2, 256);    // M = 32768
    dim3 gg2(2, 512);   // M = 65536 (merged x|y along rows)

    // fusion_x / fusion_y  (A = [x|y] concat along K=512)
    gemm_kernel<512, true,  true,  true,  true,  0, false><<<gg, 256, 0, stream>>>(xbf, ybf, w_fx1, fx_b1, nullptr, hbuf, nullptr, nullptr);
    gemm_kernel<256, false, true,  false, true,  0, false><<<gg, 256, 0, stream>>>(hbuf, nullptr, w_fx2, fx_b2, nullptr, fkx, nullptr, nullptr);
    gemm_kernel<512, true,  true,  true,  true,  0, false><<<gg, 256, 0, stream>>>(xbf, ybf, w_fy1, fy_b1, nullptr, hbuf, nullptr, nullptr);
    gemm_kernel<256, false, true,  false, true,  0, false><<<gg, 256, 0, stream>>>(hbuf, nullptr, w_fy2, fy_b2, nullptr, fky, nullptr, nullptr);

    // q MLP over [x;y]  (stage2 fuses per-column norm2 -> norm2[0..3])
    gemm_kernel<256, false, true,  true,  true,  0, false><<<gg2, 256, 0, stream>>>(xbf, nullptr, w_q1, q_b1, nullptr, hbuf, nullptr, nullptr);
    gemm_kernel<256, false, false, false, true,  0, true ><<<gg2, 256, 0, stream>>>(hbuf, nullptr, w_q2, nullptr, nullptr, qx, nullptr, norm2);
    // v MLP over [x;y]
    gemm_kernel<256, false, true,  true,  true,  0, false><<<gg2, 256, 0, stream>>>(xbf, nullptr, w_v1, v_b1, nullptr, hbuf, nullptr, nullptr);
    gemm_kernel<256, false, false, false, true,  0, false><<<gg2, 256, 0, stream>>>(hbuf, nullptr, w_v2, nullptr, nullptr, vx, nullptr, nullptr);
    // k MLP over [fkx;fky]  (stage2 norms -> norm2[4..7]; kx/ky alias fkx/fky)
    gemm_kernel<256, false, true,  true,  true,  0, false><<<gg2, 256, 0, stream>>>(fkx, nullptr, w_k1, k_b1, nullptr, hbuf, nullptr, nullptr);
    gemm_kernel<256, false, false, false, true,  0, true ><<<gg2, 256, 0, stream>>>(hbuf, nullptr, w_k2, nullptr, nullptr, kx, nullptr, norm2 + 1024);

    // attention statistics
    gram_kernel<<<512, 256, 0, stream>>>(qx, kx, qy, ky, gram);
    attn_pw_kernel<<<32, 256, 0, stream>>>(gram, norm2, rescale_x, rescale_y, px_w, py_w, PW);

    // merged project-out: rows [vx_b0, vx_b1, vy_b0, vy_b1], PW quarter per 16K rows
    gemm_kernel<256, false, true, false, false, 1, false><<<gg2, 256, 0, stream>>>(vx, nullptr, PW, px_b, py_b, nullptr, outx, nullptr);

    // pos_emb chains
    dwconv_kernel<true ><<<1024, 256, 0, stream>>>(vx, peT1, pe_b1, hbuf, nullptr);
    dwconv_kernel<false><<<1024, 256, 0, stream>>>(hbuf, peT2, pe_b2, nullptr, outx);
    dwconv_kernel<true ><<<1024, 256, 0, stream>>>(vy, peT1, pe_b1, hbuf + 16777216 / 2, nullptr);
    dwconv_kernel<false><<<1024, 256, 0, stream>>>(hbuf + 16777216 / 2, peT2, pe_b2, nullptr, outy);
}

// Round 3
// 475.725 us; speedup vs baseline: 2.1176x; 1.0772x over previous
//
#include <hip/hip_runtime.h>
#include <hip/hip_bf16.h>

typedef __hip_bfloat16 bf16;
typedef __attribute__((ext_vector_type(8))) short short8;
typedef __attribute__((ext_vector_type(4))) short short4v;
typedef __attribute__((ext_vector_type(4))) float f32x4;

// ---------- helpers ----------
static __device__ __forceinline__ float bfbits2f(short s) {
    return __uint_as_float(((unsigned int)(unsigned short)s) << 16);
}
static __device__ __forceinline__ float bf2f(bf16 v) { return __bfloat162float(v); }
static __device__ __forceinline__ bf16 f2bf(float v) { return __float2bfloat16(v); }
static __device__ __forceinline__ short f2bfbits(float f) {
    bf16 h = __float2bfloat16(f);
    return *reinterpret_cast<short*>(&h);
}

// ======================================================================
// fp32 -> bf16 conversion kernels
// ======================================================================
__launch_bounds__(256)
__global__ void cvt_xy_kernel(const float* __restrict__ x, const float* __restrict__ y,
                              bf16* __restrict__ xb, bf16* __restrict__ yb)
{
    int t = blockIdx.x * 256 + threadIdx.x;
    int which = t >> 20;
    size_t i = (size_t)(t & 1048575) * 8;
    const float4* s = (const float4*)((which ? y : x) + i);
    float4 a = s[0], b = s[1];
    short8 p;
    p[0] = f2bfbits(a.x); p[1] = f2bfbits(a.y); p[2] = f2bfbits(a.z); p[3] = f2bfbits(a.w);
    p[4] = f2bfbits(b.x); p[5] = f2bfbits(b.y); p[6] = f2bfbits(b.z); p[7] = f2bfbits(b.w);
    *(short8*)((which ? yb : xb) + i) = p;
}

struct WTab {
    const float* src[10];
    bf16* dst[10];
    int nblk[10];
};

__launch_bounds__(256)
__global__ void cvt_w_kernel(WTab tab)
{
    int b = blockIdx.x;
    int a = 0, base = 0;
    while (a < 9 && b >= base + tab.nblk[a]) { base += tab.nblk[a]; ++a; }
    int lb = b - base;
    size_t i = ((size_t)lb * 256 + threadIdx.x) * 4;
    const float4 v = *(const float4*)(tab.src[a] + i);
    bf16* d = tab.dst[a] + i;
    d[0] = f2bf(v.x); d[1] = f2bf(v.y); d[2] = f2bf(v.z); d[3] = f2bf(v.w);
}

// transpose PE dwconv weights (C,1,3,3) -> [tap][channel] fp32
__launch_bounds__(256)
__global__ void cvt_pe_kernel(const float* __restrict__ w1, const float* __restrict__ w2,
                              float* __restrict__ t1, float* __restrict__ t2)
{
    int t = blockIdx.x * 256 + threadIdx.x;
    if (t >= 4608) return;
    int which = t >= 2304;
    int i = which ? t - 2304 : t;
    int c = i / 9, k = i % 9;
    (which ? t2 : t1)[k * 256 + c] = (which ? w2 : w1)[i];
}

// ======================================================================
// Fused 2-layer MLP / single GEMM kernel.
// Tile: M=128, N=256 (full), 8 waves (512 thr), 16x16x32 bf16 MFMA.
// stage1: A(Mx K1) @ B1(256 x K1)^T (+b1, lrelu)  -> h in LDS (bf16)
// stage2: h @ W2(256x256)^T (+b2 if B2)           -> out
// TRANSOUT: write outT[col][row] (channel-major) + per-column sumsq -> nrm.
// PROJ (STAGE2=false): B1 selected per 16K-row quarter; bias b1/b2v per half.
// ======================================================================
template<int ROWS>
static __device__ __forceinline__ void stage8(const bf16* __restrict__ g, int ldk,
                                              char* dst, int tid, long r0, int k0)
{
#pragma unroll
    for (int r = 0; r < ROWS / 128; ++r) {
        int row = r * 128 + (tid >> 2);
        int q = (tid & 3) * 16;
        int srcq = q ^ (((row >> 1) & 3) << 4);
        const char* gsrc = (const char*)(g + (size_t)(r0 + row) * ldk + k0) + srcq;
        char* ldst = dst + r * 8192 + ((tid >> 6) << 10);
        __builtin_amdgcn_global_load_lds(
            (const __attribute__((address_space(1))) unsigned int*)gsrc,
            (__attribute__((address_space(3))) unsigned int*)ldst, 16, 0, 0);
    }
}

// h LDS layout: elem (r,c) at byte ((r*264 + c)*2) ^ (((r>>2)&3)<<4)
// -> conflict-free scalar writes, ~free b128 reads, 16B-aligned.
static __device__ __forceinline__ int h_off(int r, int c)
{
    return ((r * 264 + c) * 2) ^ (((r >> 2) & 3) << 4);
}

template<int K1, bool CONCAT, bool STAGE2, bool B2, bool TRANSOUT, bool PROJ>
__launch_bounds__(512)
__global__ void mlp_kernel(const bf16* __restrict__ A0, const bf16* __restrict__ A1,
                           const bf16* __restrict__ B1, const float* __restrict__ b1,
                           const bf16* __restrict__ W2, const float* __restrict__ b2v,
                           bf16* __restrict__ outb, bf16* __restrict__ outT,
                           float* __restrict__ outf, float* __restrict__ nrm)
{
    constexpr int LDS_SZ = STAGE2 ? 67584 : 49152;
    __shared__ __align__(16) char lds[LDS_SZ];
    int tid = threadIdx.x;
    int lane = tid & 63, wid = tid >> 6;
    int wr = wid >> 2, wc = wid & 3;           // 2 x 4 wave grid, wave tile 64x64
    long m0 = (long)blockIdx.y * 128;
    const bf16* Bp = B1;
    if (PROJ) Bp += (size_t)(m0 >> 14) * 65536;
    char* Abuf = lds;                           // 2 x 8192
    char* Bbuf = lds + 16384;                   // 2 x 16384

    f32x4 acc[4][4];
#pragma unroll
    for (int i = 0; i < 4; ++i)
#pragma unroll
        for (int j = 0; j < 4; ++j) acc[i][j] = (f32x4){0.f, 0.f, 0.f, 0.f};

    stage8<128>(A0, 256, Abuf, tid, m0, 0);
    stage8<256>(Bp, K1, Bbuf, tid, 0, 0);

    int kb = (lane >> 4) * 16;
    int offa[4], offb[4];
#pragma unroll
    for (int mi = 0; mi < 4; ++mi) {
        int row = wr * 64 + mi * 16 + (lane & 15);
        offa[mi] = row * 64 + (kb ^ (((row >> 1) & 3) << 4));
    }
#pragma unroll
    for (int ni = 0; ni < 4; ++ni) {
        int row = wc * 64 + ni * 16 + (lane & 15);
        offb[ni] = row * 64 + (kb ^ (((row >> 1) & 3) << 4));
    }

    constexpr int NT1 = K1 / 32;
    for (int kt = 0; kt < NT1; ++kt) {
        __syncthreads();
        int cur = kt & 1;
        if (kt + 1 < NT1) {
            int k0 = (kt + 1) * 32;
            const bf16* As = A0; int kk = k0;
            if (CONCAT && k0 >= 256) { As = A1; kk = k0 - 256; }
            stage8<128>(As, 256, Abuf + (cur ^ 1) * 8192, tid, m0, kk);
            stage8<256>(Bp, K1, Bbuf + (cur ^ 1) * 16384, tid, 0, k0);
        }
        const char* As = Abuf + cur * 8192;
        const char* Bs = Bbuf + cur * 16384;
        short8 af[4], bfr[4];
#pragma unroll
        for (int mi = 0; mi < 4; ++mi) af[mi] = *(const short8*)(As + offa[mi]);
#pragma unroll
        for (int ni = 0; ni < 4; ++ni) bfr[ni] = *(const short8*)(Bs + offb[ni]);
#pragma unroll
        for (int mi = 0; mi < 4; ++mi)
#pragma unroll
            for (int ni = 0; ni < 4; ++ni)
                acc[mi][ni] = __builtin_amdgcn_mfma_f32_16x16x32_bf16(af[mi], bfr[ni], acc[mi][ni], 0, 0, 0);
    }

    if constexpr (STAGE2) {
        float bv1[4];
#pragma unroll
        for (int ni = 0; ni < 4; ++ni) bv1[ni] = b1[wc * 64 + ni * 16 + (lane & 15)];
        __syncthreads();   // staging reads done; safe to clobber with h
#pragma unroll
        for (int mi = 0; mi < 4; ++mi)
#pragma unroll
            for (int ni = 0; ni < 4; ++ni) {
                int c = wc * 64 + ni * 16 + (lane & 15);
#pragma unroll
                for (int j = 0; j < 4; ++j) {
                    int r = wr * 64 + mi * 16 + (lane >> 4) * 4 + j;
                    float v = acc[mi][ni][j] + bv1[ni];
                    v = v > 0.f ? v : 0.01f * v;
                    *(bf16*)(lds + h_off(r, c)) = f2bf(v);
                }
            }
        __syncthreads();
        f32x4 acc2[4][4];
#pragma unroll
        for (int i = 0; i < 4; ++i)
#pragma unroll
            for (int j = 0; j < 4; ++j) acc2[i][j] = (f32x4){0.f, 0.f, 0.f, 0.f};
#pragma unroll
        for (int kc = 0; kc < 8; ++kc) {
            short8 af2[4], bf2[4];
#pragma unroll
            for (int mi = 0; mi < 4; ++mi) {
                int rm = wr * 64 + mi * 16 + (lane & 15);
                af2[mi] = *(const short8*)(lds + h_off(rm, kc * 32 + (lane >> 4) * 8));
            }
#pragma unroll
            for (int ni = 0; ni < 4; ++ni) {
                int ro = wc * 64 + ni * 16 + (lane & 15);
                bf2[ni] = *(const short8*)(W2 + ro * 256 + kc * 32 + (lane >> 4) * 8);
            }
#pragma unroll
            for (int mi = 0; mi < 4; ++mi)
#pragma unroll
                for (int ni = 0; ni < 4; ++ni)
                    acc2[mi][ni] = __builtin_amdgcn_mfma_f32_16x16x32_bf16(af2[mi], bf2[ni], acc2[mi][ni], 0, 0, 0);
        }
#pragma unroll
        for (int mi = 0; mi < 4; ++mi)
#pragma unroll
            for (int ni = 0; ni < 4; ++ni) acc[mi][ni] = acc2[mi][ni];
    }

    // ---------------- epilogue ----------------
    float bvo[4];
#pragma unroll
    for (int ni = 0; ni < 4; ++ni) {
        int col = wc * 64 + ni * 16 + (lane & 15);
        if (PROJ)            bvo[ni] = (m0 >= 32768 ? b2v : b1)[col];
        else if (B2)         bvo[ni] = b2v[col];
        else                 bvo[ni] = 0.f;
    }
    long r0 = m0 + wr * 64;
    float vsq[4] = {0.f, 0.f, 0.f, 0.f};
#pragma unroll
    for (int mi = 0; mi < 4; ++mi)
#pragma unroll
        for (int ni = 0; ni < 4; ++ni) {
            int col = wc * 64 + ni * 16 + (lane & 15);
            if (TRANSOUT) {
                short4v pk;
#pragma unroll
                for (int j = 0; j < 4; ++j) {
                    float v = acc[mi][ni][j];
                    vsq[ni] += v * v;
                    pk[j] = f2bfbits(v);
                }
                long row = r0 + mi * 16 + (lane >> 4) * 4;
                *(short4v*)(outT + (size_t)col * 65536 + row) = pk;
            } else {
#pragma unroll
                for (int j = 0; j < 4; ++j) {
                    size_t row = (size_t)(r0 + mi * 16 + (lane >> 4) * 4 + j);
                    float v = acc[mi][ni][j] + bvo[ni];
                    if (PROJ) outf[row * 256 + col] = v;
                    else      outb[row * 256 + col] = f2bf(v);
                }
            }
        }
    if constexpr (TRANSOUT) {
        __syncthreads();
        float* cs = (float*)lds;
        if (tid < 256) cs[tid] = 0.f;
        __syncthreads();
#pragma unroll
        for (int ni = 0; ni < 4; ++ni)
            atomicAdd(&cs[wc * 64 + ni * 16 + (lane & 15)], vsq[ni]);
        __syncthreads();
        if (tid < 256)
            atomicAdd(nrm + (int)(m0 >> 14) * 256 + tid, cs[tid]);
    }
}

// ======================================================================
// MFMA Gram: gram[pair][b][h][d][e] = sum_n K[n][h*32+d] * Q[n][h*32+e]
// qT/kT channel-major [256][65536]; rows = [x_b0, x_b1, y_b0, y_b1].
// pair0: K=ky, Q=qx.  pair1: K=kx, Q=qy.
// grid: ((pair*2+b)*8+h)*16 + ns  (512 blocks, 4 waves, 256 n per wave)
// ======================================================================
__launch_bounds__(256)
__global__ void gram_mfma_kernel(const bf16* __restrict__ qT, const bf16* __restrict__ kT,
                                 float* __restrict__ gram)
{
    __shared__ float g[1024];
    int bid = blockIdx.x;
    int ns = bid & 15, h = (bid >> 4) & 7, b = (bid >> 7) & 1, pair = bid >> 8;
    int tid = threadIdx.x;
    int lane = tid & 63, w = tid >> 6;
    long krow = pair ? (long)b * 16384 : (long)(32768 + b * 16384);
    long qrow = pair ? (long)(32768 + b * 16384) : (long)b * 16384;
    long nb = (long)ns * 1024 + w * 256 + (lane >> 4) * 8;
    const bf16* Kp = kT + krow + nb;
    const bf16* Qp = qT + qrow + nb;
    int ch = h * 32 + (lane & 15);

    f32x4 acc[2][2];
#pragma unroll
    for (int i = 0; i < 2; ++i)
#pragma unroll
        for (int j = 0; j < 2; ++j) acc[i][j] = (f32x4){0.f, 0.f, 0.f, 0.f};

    for (int it = 0; it < 8; ++it) {
        short8 af[2], bfr[2];
#pragma unroll
        for (int mi = 0; mi < 2; ++mi)
            af[mi] = *(const short8*)(Kp + (size_t)(ch + mi * 16) * 65536 + it * 32);
#pragma unroll
        for (int ni = 0; ni < 2; ++ni)
            bfr[ni] = *(const short8*)(Qp + (size_t)(ch + ni * 16) * 65536 + it * 32);
#pragma unroll
        for (int mi = 0; mi < 2; ++mi)
#pragma unroll
            for (int ni = 0; ni < 2; ++ni)
                acc[mi][ni] = __builtin_amdgcn_mfma_f32_16x16x32_bf16(af[mi], bfr[ni], acc[mi][ni], 0, 0, 0);
    }

#pragma unroll
    for (int k = 0; k < 4; ++k) g[tid + k * 256] = 0.f;
    __syncthreads();
#pragma unroll
    for (int mi = 0; mi < 2; ++mi)
#pragma unroll
        for (int ni = 0; ni < 2; ++ni) {
            int e = ni * 16 + (lane & 15);
#pragma unroll
            for (int j = 0; j < 4; ++j) {
                int d = mi * 16 + (lane >> 4) * 4 + j;
                atomicAdd(&g[d * 32 + e], acc[mi][ni][j]);
            }
        }
    __syncthreads();
    float* gp = gram + ((size_t)((pair * 2 + b) * 8 + h)) * 1024;
#pragma unroll
    for (int k = 0; k < 4; ++k)
        atomicAdd(gp + tid + k * 256, g[tid + k * 256]);
}

// ======================================================================
// softmax + fold attention into project-out weights
// norm2: [qx_b0,qx_b1,qy_b0,qy_b1, kx_b0,kx_b1,ky_b0,ky_b1][256]
// ======================================================================
__launch_bounds__(256)
__global__ void attn_pw_kernel(const float* __restrict__ gram, const float* __restrict__ norm2,
                               const float* __restrict__ rsx, const float* __restrict__ rsy,
                               const float* __restrict__ pxw, const float* __restrict__ pyw,
                               bf16* __restrict__ PW)
{
    int bid = blockIdx.x;                 // pair*16 + b*8 + h
    int h = bid & 7, b = (bid >> 3) & 1, pair = bid >> 4;
    const float* G = gram + ((size_t)((pair * 2 + b) * 8 + h)) * 1024;
    const float* nk2 = norm2 + (pair ? (4 + b) : (6 + b)) * 256 + h * 32;
    const float* nq2 = norm2 + (pair ? (2 + b) : (0 + b)) * 256 + h * 32;
    float rs = (pair ? rsy : rsx)[h];
    __shared__ float attn[32][32];
    int t = threadIdx.x;
    if (t < 32) {
        int d = t;
        float nk = fmaxf(sqrtf(nk2[d]), 1e-12f);
        float row[32];
        float mx = -3.4e38f;
#pragma unroll
        for (int e = 0; e < 32; ++e) {
            float nq = fmaxf(sqrtf(nq2[e]), 1e-12f);
            float L = G[d * 32 + e] / (nk * nq) * rs;
            row[e] = L;
            mx = fmaxf(mx, L);
        }
        float sum = 0.f;
#pragma unroll
        for (int e = 0; e < 32; ++e) { row[e] = expf(row[e] - mx); sum += row[e]; }
        float inv = 1.0f / sum;
#pragma unroll
        for (int e = 0; e < 32; ++e) attn[d][e] = row[e] * inv;
    }
    __syncthreads();
    const float* pw = pair ? pyw : pxw;
    int o = t;
    float wrow[32];
#pragma unroll
    for (int d2 = 0; d2 < 32; ++d2) wrow[d2] = pw[o * 256 + h * 32 + d2];
    bf16* dst = PW + ((size_t)(pair * 2 + b) * 256 + o) * 256 + h * 32;
#pragma unroll
    for (int e = 0; e < 32; ++e) {
        float sv = 0.f;
#pragma unroll
        for (int d2 = 0; d2 < 32; ++d2) sv += wrow[d2] * attn[d2][e];
        dst[e] = f2bf(sv);
    }
}

// ======================================================================
// depthwise 3x3 conv, NHWC (2,128,128,256), zero pad.
// ======================================================================
template<bool GELU_OUT_BF>
__launch_bounds__(256)
__global__ void dwconv_kernel(const bf16* __restrict__ in, const float* __restrict__ wT,
                              const float* __restrict__ bias, bf16* __restrict__ outb,
                              float* __restrict__ outf)
{
    int t = blockIdx.x * 256 + threadIdx.x;   // 1024 blocks
    int cg = t & 31;
    int x = (t >> 5) & 127;
    int chunk = (t >> 12) & 31;
    int b = t >> 17;
    int c0 = cg * 8;

    float w[9][8];
#pragma unroll
    for (int k = 0; k < 9; ++k) {
        float4 a = *(const float4*)(wT + k * 256 + c0);
        float4 bq = *(const float4*)(wT + k * 256 + c0 + 4);
        w[k][0] = a.x; w[k][1] = a.y; w[k][2] = a.z; w[k][3] = a.w;
        w[k][4] = bq.x; w[k][5] = bq.y; w[k][6] = bq.z; w[k][7] = bq.w;
    }
    float bs[8];
    {
        float4 a = *(const float4*)(bias + c0);
        float4 bq = *(const float4*)(bias + c0 + 4);
        bs[0] = a.x; bs[1] = a.y; bs[2] = a.z; bs[3] = a.w;
        bs[4] = bq.x; bs[5] = bq.y; bs[6] = bq.z; bs[7] = bq.w;
    }
    const short8 z = (short8){0, 0, 0, 0, 0, 0, 0, 0};
    bool xm = x > 0, xp = x < 127;
    int y0 = chunk * 4;

    for (int yi = 0; yi < 4; ++yi) {
        int y = y0 + yi;
        float acc[8];
#pragma unroll
        for (int j = 0; j < 8; ++j) acc[j] = bs[j];
#pragma unroll
        for (int ky = -1; ky <= 1; ++ky) {
            int yy = y + ky;
            if (yy < 0 || yy > 127) continue;
            const bf16* rp = in + ((((size_t)b << 14) + (yy << 7) + x) << 8) + c0;
            short8 vm = xm ? *(const short8*)(rp - 256) : z;
            short8 vc = *(const short8*)(rp);
            short8 vp = xp ? *(const short8*)(rp + 256) : z;
            int k0 = (ky + 1) * 3;
#pragma unroll
            for (int j = 0; j < 8; ++j) {
                acc[j] += w[k0 + 0][j] * bfbits2f(vm[j]);
                acc[j] += w[k0 + 1][j] * bfbits2f(vc[j]);
                acc[j] += w[k0 + 2][j] * bfbits2f(vp[j]);
            }
        }
        size_t base = ((((size_t)b << 14) + (y << 7) + x) << 8) + c0;
        if (GELU_OUT_BF) {
            short8 p;
#pragma unroll
            for (int j = 0; j < 8; ++j) {
                float a = acc[j];
                a = 0.5f * a * (1.0f + erff(a * 0.70710678118654752f));
                p[j] = f2bfbits(a);
            }
            *(short8*)(outb + base) = p;
        } else {
            float4* o = (float4*)(outf + base);
            float4 o0 = o[0], o1 = o[1];
            o0.x += acc[0]; o0.y += acc[1]; o0.z += acc[2]; o0.w += acc[3];
            o1.x += acc[4]; o1.y += acc[5]; o1.z += acc[6]; o1.w += acc[7];
            o[0] = o0; o[1] = o1;
        }
    }
}

// ======================================================================
// launch
// ======================================================================
extern "C" void kernel_launch(void* const* d_in, const int* in_sizes, int n_in,
                              void* d_out, int out_size, void* d_ws, size_t ws_size,
                              hipStream_t stream)
{
    const float* x_in  = (const float*)d_in[0];
    const float* y_in  = (const float*)d_in[1];
    const float* fx_w1 = (const float*)d_in[2];
    const float* fx_b1 = (const float*)d_in[3];
    const float* fx_w2 = (const float*)d_in[4];
    const float* fx_b2 = (const float*)d_in[5];
    const float* fy_w1 = (const float*)d_in[6];
    const float* fy_b1 = (const float*)d_in[7];
    const float* fy_w2 = (const float*)d_in[8];
    const float* fy_b2 = (const float*)d_in[9];
    const float* q_w1  = (const float*)d_in[10];
    const float* q_b1  = (const float*)d_in[11];
    const float* q_w2  = (const float*)d_in[12];
    const float* k_w1  = (const float*)d_in[13];
    const float* k_b1  = (const float*)d_in[14];
    const float* k_w2  = (const float*)d_in[15];
    const float* v_w1  = (const float*)d_in[16];
    const float* v_b1  = (const float*)d_in[17];
    const float* v_w2  = (const float*)d_in[18];
    const float* rescale_x = (const float*)d_in[19];
    const float* rescale_y = (const float*)d_in[20];
    const float* px_w  = (const float*)d_in[21];
    const float* px_b  = (const float*)d_in[22];
    const float* py_w  = (const float*)d_in[23];
    const float* py_b  = (const float*)d_in[24];
    const float* pe_w1 = (const float*)d_in[25];
    const float* pe_b1 = (const float*)d_in[26];
    const float* pe_w2 = (const float*)d_in[27];
    const float* pe_b2 = (const float*)d_in[28];

    char* ws = (char*)d_ws;
    const size_t NB = 16777216;
    bf16* xbf  = (bf16*)(ws + 0 * NB);    // [xb | yb] adjacent = 65536-row A
    bf16* ybf  = (bf16*)(ws + 1 * NB);
    bf16* fkx  = (bf16*)(ws + 2 * NB);    // [fkx | fky] adjacent; slot2 = conv temp later
    bf16* fky  = (bf16*)(ws + 3 * NB);
    bf16* vbuf = (bf16*)(ws + 4 * NB);    // 65536 rows [vx_b0,vx_b1,vy_b0,vy_b1]
    bf16* qT   = (bf16*)(ws + 6 * NB);    // [256][65536] channel-major
    bf16* kT   = (bf16*)(ws + 8 * NB);
    char* wreg = ws + 10 * NB;
    bf16* w_fx1 = (bf16*)(wreg + 0);
    bf16* w_fx2 = (bf16*)(wreg + 262144);
    bf16* w_fy1 = (bf16*)(wreg + 393216);
    bf16* w_fy2 = (bf16*)(wreg + 655360);
    bf16* w_q1  = (bf16*)(wreg + 786432);
    bf16* w_q2  = (bf16*)(wreg + 917504);
    bf16* w_k1  = (bf16*)(wreg + 1048576);
    bf16* w_k2  = (bf16*)(wreg + 1179648);
    bf16* w_v1  = (bf16*)(wreg + 1310720);
    bf16* w_v2  = (bf16*)(wreg + 1441792);
    float* gram  = (float*)(wreg + 1572864);             // 128 KB
    float* norm2 = (float*)(wreg + 1572864 + 131072);    // 8 KB
    bf16* PW     = (bf16*)(wreg + 1572864 + 139264);     // 512 KB
    float* peT1  = (float*)(wreg + 1572864 + 139264 + 524288);
    float* peT2  = (float*)(wreg + 1572864 + 139264 + 524288 + 9216);
    bf16* ctmp   = (bf16*)(ws + 2 * NB);  // conv temp reuses fkx (dead after k-MLP)

    float* outx = (float*)d_out;
    float* outy = outx + 8388608;

    hipMemsetAsync(gram, 0, 139264, stream);   // gram + norm2

    cvt_xy_kernel<<<8192, 256, 0, stream>>>(x_in, y_in, xbf, ybf);
    WTab tab;
    const float* ws_src[10] = {fx_w1, fx_w2, fy_w1, fy_w2, q_w1, q_w2, k_w1, k_w2, v_w1, v_w2};
    bf16* ws_dst[10] = {w_fx1, w_fx2, w_fy1, w_fy2, w_q1, w_q2, w_k1, w_k2, w_v1, w_v2};
    int nblk[10] = {128, 64, 128, 64, 64, 64, 64, 64, 64, 64};
    for (int i = 0; i < 10; ++i) { tab.src[i] = ws_src[i]; tab.dst[i] = ws_dst[i]; tab.nblk[i] = nblk[i]; }
    cvt_w_kernel<<<768, 256, 0, stream>>>(tab);
    cvt_pe_kernel<<<18, 256, 0, stream>>>(pe_w1, pe_w2, peT1, peT2);

    dim3 g256(1, 256), g512(1, 512);
    // fusion_x / fusion_y: K=512 concat [x|y] -> lrelu -> W2 + b2 -> fk
    mlp_kernel<512, true,  true,  true,  false, false><<<g256, 512, 0, stream>>>(
        xbf, ybf, w_fx1, fx_b1, w_fx2, fx_b2, fkx, nullptr, nullptr, nullptr);
    mlp_kernel<512, true,  true,  true,  false, false><<<g256, 512, 0, stream>>>(
        xbf, ybf, w_fy1, fy_b1, w_fy2, fy_b2, fky, nullptr, nullptr, nullptr);
    // q MLP over [x;y] -> qT (channel-major) + norm2[0..3]
    mlp_kernel<256, false, true,  false, true,  false><<<g512, 512, 0, stream>>>(
        xbf, nullptr, w_q1, q_b1, w_q2, nullptr, nullptr, qT, nullptr, norm2);
    // v MLP over [x;y] -> vbuf
    mlp_kernel<256, false, true,  false, false, false><<<g512, 512, 0, stream>>>(
        xbf, nullptr, w_v1, v_b1, w_v2, nullptr, vbuf, nullptr, nullptr, nullptr);
    // k MLP over [fkx;fky] -> kT + norm2[4..7]
    mlp_kernel<256, false, true,  false, true,  false><<<g512, 512, 0, stream>>>(
        fkx, nullptr, w_k1, k_b1, w_k2, nullptr, nullptr, kT, nullptr, norm2 + 1024);

    // attention statistics
    gram_mfma_kernel<<<512, 256, 0, stream>>>(qT, kT, gram);
    attn_pw_kernel<<<32, 256, 0, stream>>>(gram, norm2, rescale_x, rescale_y, px_w, py_w, PW);

    // merged project-out (PW quarter + bias select per 16K rows) -> fp32 out
    mlp_kernel<256, false, false, false, false, true><<<g512, 512, 0, stream>>>(
        vbuf, nullptr, PW, px_b, nullptr, py_b, nullptr, nullptr, outx, nullptr);

    // pos_emb chains
    dwconv_kernel<true ><<<1024, 256, 0, stream>>>(vbuf, peT1, pe_b1, ctmp, nullptr);
    dwconv_kernel<false><<<1024, 256, 0, stream>>>(ctmp, peT2, pe_b2, nullptr, outx);
    dwconv_kernel<true ><<<1024, 256, 0, stream>>>(vbuf + (size_t)32768 * 256, peT1, pe_b1, ctmp, nullptr);
    dwconv_kernel<false><<<1024, 256, 0, stream>>>(ctmp, peT2, pe_b2, nullptr, outy);
}

// Round 4
// 443.831 us; speedup vs baseline: 2.2697x; 1.0719x over previous
//
#include <hip/hip_runtime.h>
#include <hip/hip_bf16.h>

typedef __hip_bfloat16 bf16;
typedef __attribute__((ext_vector_type(8))) short short8;
typedef __attribute__((ext_vector_type(4))) float f32x4;

// ---------- helpers ----------
static __device__ __forceinline__ float bfbits2f(short s) {
    return __uint_as_float(((unsigned int)(unsigned short)s) << 16);
}
static __device__ __forceinline__ float bf2f(bf16 v) { return __bfloat162float(v); }
static __device__ __forceinline__ bf16 f2bf(float v) { return __float2bfloat16(v); }
static __device__ __forceinline__ short f2bfbits(float f) {
    bf16 h = __float2bfloat16(f);
    return *reinterpret_cast<short*>(&h);
}

// ======================================================================
// prep: xy fp32->bf16 cast | weight casts | PE weight transpose | zeroing
// grid = 8192 + 768 + 18 + 34 = 9012 blocks x 256
// ======================================================================
struct PrepArgs {
    const float *x, *y; bf16 *xb, *yb;
    const float* wsrc[10]; bf16* wdst[10]; int wblk[10];
    const float *pw1, *pw2; float *t1, *t2;
    float4* zero;                       // 34*256 float4 = 139264 B (gram+norm2)
};

__launch_bounds__(256)
__global__ void prep_kernel(PrepArgs a)
{
    int blk = blockIdx.x, tid = threadIdx.x;
    if (blk < 8192) {
        int t = blk * 256 + tid;
        int which = t >> 20;
        size_t i = (size_t)(t & 1048575) * 8;
        const float4* s = (const float4*)((which ? a.y : a.x) + i);
        float4 u = s[0], v = s[1];
        short8 p;
        p[0] = f2bfbits(u.x); p[1] = f2bfbits(u.y); p[2] = f2bfbits(u.z); p[3] = f2bfbits(u.w);
        p[4] = f2bfbits(v.x); p[5] = f2bfbits(v.y); p[6] = f2bfbits(v.z); p[7] = f2bfbits(v.w);
        *(short8*)((which ? a.yb : a.xb) + i) = p;
    } else if (blk < 8960) {
        int b = blk - 8192;
        int ai = 0, base = 0;
        while (ai < 9 && b >= base + a.wblk[ai]) { base += a.wblk[ai]; ++ai; }
        size_t i = ((size_t)(b - base) * 256 + tid) * 4;
        const float4 v = *(const float4*)(a.wsrc[ai] + i);
        bf16* d = a.wdst[ai] + i;
        d[0] = f2bf(v.x); d[1] = f2bf(v.y); d[2] = f2bf(v.z); d[3] = f2bf(v.w);
    } else if (blk < 8978) {
        int t = (blk - 8960) * 256 + tid;
        if (t < 4608) {
            int which = t >= 2304;
            int i = which ? t - 2304 : t;
            int c = i / 9, k = i % 9;
            (which ? a.t2 : a.t1)[k * 256 + c] = (which ? a.pw2 : a.pw1)[i];
        }
    } else {
        int i = (blk - 8978) * 256 + tid;
        a.zero[i] = make_float4(0.f, 0.f, 0.f, 0.f);
    }
}

// ======================================================================
// global -> LDS staging (16B, pre-swizzled source; linear LDS dest)
// ======================================================================
template<int ROWS>
static __device__ __forceinline__ void stage8(const bf16* __restrict__ g, int ldk,
                                              char* dst, int tid, long r0, int k0)
{
#pragma unroll
    for (int r = 0; r < ROWS / 128; ++r) {
        int row = r * 128 + (tid >> 2);
        int q = (tid & 3) * 16;
        int srcq = q ^ (((row >> 1) & 3) << 4);
        const char* gsrc = (const char*)(g + (size_t)(r0 + row) * ldk + k0) + srcq;
        char* ldst = dst + r * 8192 + ((tid >> 6) << 10);
        __builtin_amdgcn_global_load_lds(
            (const __attribute__((address_space(1))) unsigned int*)gsrc,
            (__attribute__((address_space(3))) unsigned int*)ldst, 16, 0, 0);
    }
}

// h buffer: [128 rows][256 cols] bf16, XOR-swizzled (65536 B, conflict-lite)
static __device__ __forceinline__ int h_off2(int r, int c)
{
    return r * 512 + ((c * 2) ^ ((r & 7) << 4));
}

// ======================================================================
// Fused 2-layer MLP, two weight-sets selected by blockIdx.x (sel).
// stage1: A(128 x K1) @ B1(256 x K1)^T + b1 -> lrelu -> h (LDS)
// stage2: h @ W2(256x256)^T [8-wave x 32-col tiling, W2 kc-prefetch]
// epilogue through LDS re-transpose -> coalesced short8 stores.
// TRANS0 && sel==0: channel-major outT[col][row] + per-col sumsq -> nrm.
// ======================================================================
struct MlpArgs {
    const bf16* B1[2]; const float* b1[2];
    const bf16* W2[2]; const float* b2[2];
    bf16* outb[2]; bf16* outT[2]; float* nrm[2];
};

template<int K1, bool CONCAT, bool B2OUT, bool TRANS0>
__launch_bounds__(512, 4)
__global__ void mlp_kernel(const bf16* __restrict__ A0, const bf16* __restrict__ A1,
                           MlpArgs args)
{
    __shared__ __align__(16) char lds[66560];
    int tid = threadIdx.x;
    int lane = tid & 63, wid = tid >> 6;
    int c16 = lane & 15, kg = lane >> 4;
    int wr = wid >> 2, wc = wid & 3;            // stage1: 2x4 waves, 64x64 tiles
    int sel = blockIdx.x;
    long m0 = (long)blockIdx.y * 128;
    const bf16* B1p = args.B1[sel];
    const bf16* W2p = args.W2[sel];
    char* Abuf = lds;                            // 2 x 8192
    char* Bbuf = lds + 16384;                    // 2 x 16384

    f32x4 acc[4][4];
#pragma unroll
    for (int i = 0; i < 4; ++i)
#pragma unroll
        for (int j = 0; j < 4; ++j) acc[i][j] = (f32x4){0.f, 0.f, 0.f, 0.f};

    stage8<128>(A0, 256, Abuf, tid, m0, 0);
    stage8<256>(B1p, K1, Bbuf, tid, 0, 0);

    int kb = kg * 16;
    int offa[4], offb[4];
#pragma unroll
    for (int mi = 0; mi < 4; ++mi) {
        int row = wr * 64 + mi * 16 + c16;
        offa[mi] = row * 64 + (kb ^ (((row >> 1) & 3) << 4));
    }
#pragma unroll
    for (int ni = 0; ni < 4; ++ni) {
        int row = wc * 64 + ni * 16 + c16;
        offb[ni] = row * 64 + (kb ^ (((row >> 1) & 3) << 4));
    }

    constexpr int NT1 = K1 / 32;
    for (int kt = 0; kt < NT1; ++kt) {
        __syncthreads();
        int cur = kt & 1;
        if (kt + 1 < NT1) {
            int k0 = (kt + 1) * 32;
            const bf16* As = A0; int kk = k0;
            if (CONCAT && k0 >= 256) { As = A1; kk = k0 - 256; }
            stage8<128>(As, 256, Abuf + (cur ^ 1) * 8192, tid, m0, kk);
            stage8<256>(B1p, K1, Bbuf + (cur ^ 1) * 16384, tid, 0, k0);
        }
        const char* As = Abuf + cur * 8192;
        const char* Bs = Bbuf + cur * 16384;
        short8 af[4], bfr[4];
#pragma unroll
        for (int mi = 0; mi < 4; ++mi) af[mi] = *(const short8*)(As + offa[mi]);
#pragma unroll
        for (int ni = 0; ni < 4; ++ni) bfr[ni] = *(const short8*)(Bs + offb[ni]);
#pragma unroll
        for (int mi = 0; mi < 4; ++mi)
#pragma unroll
            for (int ni = 0; ni < 4; ++ni)
                acc[mi][ni] = __builtin_amdgcn_mfma_f32_16x16x32_bf16(af[mi], bfr[ni], acc[mi][ni], 0, 0, 0);
    }

    // ---- W2 kc=0 prefetch (no LDS dep; latency hidden under h writes) ----
    int co0 = wid * 32 + c16;
    short8 wf[2][2];
    wf[0][0] = *(const short8*)(W2p + (size_t)co0 * 256 + kg * 8);
    wf[0][1] = *(const short8*)(W2p + (size_t)(co0 + 16) * 256 + kg * 8);

    float bv1[4];
#pragma unroll
    for (int ni = 0; ni < 4; ++ni) bv1[ni] = args.b1[sel][wc * 64 + ni * 16 + c16];
    __syncthreads();   // staging reads done; lds becomes h
#pragma unroll
    for (int mi = 0; mi < 4; ++mi)
#pragma unroll
        for (int ni = 0; ni < 4; ++ni) {
            int c = wc * 64 + ni * 16 + c16;
#pragma unroll
            for (int j = 0; j < 4; ++j) {
                int r = wr * 64 + mi * 16 + kg * 4 + j;
                float v = acc[mi][ni][j] + bv1[ni];
                v = v > 0.f ? v : 0.01f * v;
                *(bf16*)(lds + h_off2(r, c)) = f2bf(v);
            }
        }
    __syncthreads();

    // ---- stage2: wave = 32 cols x 128 rows (no W2 duplication) ----
    f32x4 acc2[8][2];
#pragma unroll
    for (int i = 0; i < 8; ++i) {
        acc2[i][0] = (f32x4){0.f, 0.f, 0.f, 0.f};
        acc2[i][1] = (f32x4){0.f, 0.f, 0.f, 0.f};
    }
    for (int kc = 0; kc < 8; ++kc) {
        int cur = kc & 1;
        if (kc < 7) {
            wf[cur ^ 1][0] = *(const short8*)(W2p + (size_t)co0 * 256 + (kc + 1) * 32 + kg * 8);
            wf[cur ^ 1][1] = *(const short8*)(W2p + (size_t)(co0 + 16) * 256 + (kc + 1) * 32 + kg * 8);
        }
#pragma unroll
        for (int mi = 0; mi < 8; ++mi) {
            short8 a2 = *(const short8*)(lds + h_off2(mi * 16 + c16, kc * 32 + kg * 8));
            acc2[mi][0] = __builtin_amdgcn_mfma_f32_16x16x32_bf16(a2, wf[cur][0], acc2[mi][0], 0, 0, 0);
            acc2[mi][1] = __builtin_amdgcn_mfma_f32_16x16x32_bf16(a2, wf[cur][1], acc2[mi][1], 0, 0, 0);
        }
    }

    // ---- epilogue: LDS re-transpose -> coalesced stores ----
    bool trans = TRANS0 && (sel == 0);
    float vsq[2] = {0.f, 0.f};
    __syncthreads();   // h dead
    if (trans) {
#pragma unroll
        for (int mi = 0; mi < 8; ++mi)
#pragma unroll
            for (int j2 = 0; j2 < 2; ++j2) {
                int col = co0 + j2 * 16;
#pragma unroll
                for (int j = 0; j < 4; ++j) {
                    float v = acc2[mi][j2][j];
                    vsq[j2] += v * v;
                    int row = mi * 16 + kg * 4 + j;
                    *(bf16*)(lds + col * 256 + ((row * 2) ^ ((col & 7) << 4))) = f2bf(v);
                }
            }
    } else {
        float bvo[2];
        bvo[0] = B2OUT ? args.b2[sel][co0] : 0.f;
        bvo[1] = B2OUT ? args.b2[sel][co0 + 16] : 0.f;
#pragma unroll
        for (int mi = 0; mi < 8; ++mi)
#pragma unroll
            for (int j2 = 0; j2 < 2; ++j2) {
                int col = co0 + j2 * 16;
#pragma unroll
                for (int j = 0; j < 4; ++j) {
                    int row = mi * 16 + kg * 4 + j;
                    *(bf16*)(lds + h_off2(row, col)) = f2bf(acc2[mi][j2][j] + bvo[j2]);
                }
            }
    }
    __syncthreads();
    if (trans) {
        bf16* dst = args.outT[sel];
#pragma unroll
        for (int i = 0; i < 8; ++i) {
            int g = i * 512 + tid;
            int col = g >> 4, rc = g & 15;
            short8 vv = *(const short8*)(lds + col * 256 + ((rc ^ (col & 7)) << 4));
            *(short8*)(dst + (size_t)col * 65536 + m0 + rc * 8) = vv;
        }
        float* cs = (float*)(lds + 65536);
        if (tid < 256) cs[tid] = 0.f;
        __syncthreads();
        atomicAdd(&cs[co0], vsq[0]);
        atomicAdd(&cs[co0 + 16], vsq[1]);
        __syncthreads();
        if (tid < 256)
            atomicAdd(args.nrm[sel] + (int)(m0 >> 14) * 256 + tid, cs[tid]);
    } else {
        bf16* dst = args.outb[sel];
#pragma unroll
        for (int i = 0; i < 8; ++i) {
            int g = i * 512 + tid;
            int row = g >> 5, cc = g & 31;
            short8 vv = *(const short8*)(lds + row * 512 + ((cc ^ (row & 7)) << 4));
            *(short8*)(dst + (size_t)(m0 + row) * 256 + cc * 8) = vv;
        }
    }
}

// ======================================================================
// project-out GEMM: out[M=65536,256] = V @ PW(sel by 16K-row quarter)^T
// + bias (px_b rows<32768, py_b after) -> fp32.
// ======================================================================
__launch_bounds__(512, 6)
__global__ void proj_kernel(const bf16* __restrict__ A0, const bf16* __restrict__ Bw,
                            const float* __restrict__ bx, const float* __restrict__ by,
                            float* __restrict__ outf)
{
    __shared__ __align__(16) char lds[49152];
    int tid = threadIdx.x;
    int lane = tid & 63, wid = tid >> 6;
    int c16 = lane & 15, kg = lane >> 4;
    int wr = wid >> 2, wc = wid & 3;
    long m0 = (long)blockIdx.y * 128;
    const bf16* Bp = Bw + (size_t)(m0 >> 14) * 65536;
    char* Abuf = lds;
    char* Bbuf = lds + 16384;

    f32x4 acc[4][4];
#pragma unroll
    for (int i = 0; i < 4; ++i)
#pragma unroll
        for (int j = 0; j < 4; ++j) acc[i][j] = (f32x4){0.f, 0.f, 0.f, 0.f};

    stage8<128>(A0, 256, Abuf, tid, m0, 0);
    stage8<256>(Bp, 256, Bbuf, tid, 0, 0);

    int kb = kg * 16;
    int offa[4], offb[4];
#pragma unroll
    for (int mi = 0; mi < 4; ++mi) {
        int row = wr * 64 + mi * 16 + c16;
        offa[mi] = row * 64 + (kb ^ (((row >> 1) & 3) << 4));
    }
#pragma unroll
    for (int ni = 0; ni < 4; ++ni) {
        int row = wc * 64 + ni * 16 + c16;
        offb[ni] = row * 64 + (kb ^ (((row >> 1) & 3) << 4));
    }

    for (int kt = 0; kt < 8; ++kt) {
        __syncthreads();
        int cur = kt & 1;
        if (kt + 1 < 8) {
            int k0 = (kt + 1) * 32;
            stage8<128>(A0, 256, Abuf + (cur ^ 1) * 8192, tid, m0, k0);
            stage8<256>(Bp, 256, Bbuf + (cur ^ 1) * 16384, tid, 0, k0);
        }
        const char* As = Abuf + cur * 8192;
        const char* Bs = Bbuf + cur * 16384;
        short8 af[4], bfr[4];
#pragma unroll
        for (int mi = 0; mi < 4; ++mi) af[mi] = *(const short8*)(As + offa[mi]);
#pragma unroll
        for (int ni = 0; ni < 4; ++ni) bfr[ni] = *(const short8*)(Bs + offb[ni]);
#pragma unroll
        for (int mi = 0; mi < 4; ++mi)
#pragma unroll
            for (int ni = 0; ni < 4; ++ni)
                acc[mi][ni] = __builtin_amdgcn_mfma_f32_16x16x32_bf16(af[mi], bfr[ni], acc[mi][ni], 0, 0, 0);
    }

    const float* bsel = (m0 >= 32768) ? by : bx;
    float bv[4];
#pragma unroll
    for (int ni = 0; ni < 4; ++ni) bv[ni] = bsel[wc * 64 + ni * 16 + c16];
    long r0 = m0 + wr * 64;
#pragma unroll
    for (int mi = 0; mi < 4; ++mi)
#pragma unroll
        for (int ni = 0; ni < 4; ++ni) {
            int col = wc * 64 + ni * 16 + c16;
#pragma unroll
            for (int j = 0; j < 4; ++j) {
                size_t row = (size_t)(r0 + mi * 16 + kg * 4 + j);
                outf[row * 256 + col] = acc[mi][ni][j] + bv[ni];
            }
        }
}

// ======================================================================
// MFMA Gram (unchanged): gram[pair][b][h][d][e]
// ======================================================================
__launch_bounds__(256)
__global__ void gram_mfma_kernel(const bf16* __restrict__ qT, const bf16* __restrict__ kT,
                                 float* __restrict__ gram)
{
    __shared__ float g[1024];
    int bid = blockIdx.x;
    int ns = bid & 15, h = (bid >> 4) & 7, b = (bid >> 7) & 1, pair = bid >> 8;
    int tid = threadIdx.x;
    int lane = tid & 63, w = tid >> 6;
    long krow = pair ? (long)b * 16384 : (long)(32768 + b * 16384);
    long qrow = pair ? (long)(32768 + b * 16384) : (long)b * 16384;
    long nb = (long)ns * 1024 + w * 256 + (lane >> 4) * 8;
    const bf16* Kp = kT + krow + nb;
    const bf16* Qp = qT + qrow + nb;
    int ch = h * 32 + (lane & 15);

    f32x4 acc[2][2];
#pragma unroll
    for (int i = 0; i < 2; ++i)
#pragma unroll
        for (int j = 0; j < 2; ++j) acc[i][j] = (f32x4){0.f, 0.f, 0.f, 0.f};

    for (int it = 0; it < 8; ++it) {
        short8 af[2], bfr[2];
#pragma unroll
        for (int mi = 0; mi < 2; ++mi)
            af[mi] = *(const short8*)(Kp + (size_t)(ch + mi * 16) * 65536 + it * 32);
#pragma unroll
        for (int ni = 0; ni < 2; ++ni)
            bfr[ni] = *(const short8*)(Qp + (size_t)(ch + ni * 16) * 65536 + it * 32);
#pragma unroll
        for (int mi = 0; mi < 2; ++mi)
#pragma unroll
            for (int ni = 0; ni < 2; ++ni)
                acc[mi][ni] = __builtin_amdgcn_mfma_f32_16x16x32_bf16(af[mi], bfr[ni], acc[mi][ni], 0, 0, 0);
    }

#pragma unroll
    for (int k = 0; k < 4; ++k) g[tid + k * 256] = 0.f;
    __syncthreads();
#pragma unroll
    for (int mi = 0; mi < 2; ++mi)
#pragma unroll
        for (int ni = 0; ni < 2; ++ni) {
            int e = ni * 16 + (lane & 15);
#pragma unroll
            for (int j = 0; j < 4; ++j) {
                int d = mi * 16 + (lane >> 4) * 4 + j;
                atomicAdd(&g[d * 32 + e], acc[mi][ni][j]);
            }
        }
    __syncthreads();
    float* gp = gram + ((size_t)((pair * 2 + b) * 8 + h)) * 1024;
#pragma unroll
    for (int k = 0; k < 4; ++k)
        atomicAdd(gp + tid + k * 256, g[tid + k * 256]);
}

// ======================================================================
// softmax + fold attention into project-out weights (unchanged)
// ======================================================================
__launch_bounds__(256)
__global__ void attn_pw_kernel(const float* __restrict__ gram, const float* __restrict__ norm2,
                               const float* __restrict__ rsx, const float* __restrict__ rsy,
                               const float* __restrict__ pxw, const float* __restrict__ pyw,
                               bf16* __restrict__ PW)
{
    int bid = blockIdx.x;
    int h = bid & 7, b = (bid >> 3) & 1, pair = bid >> 4;
    const float* G = gram + ((size_t)((pair * 2 + b) * 8 + h)) * 1024;
    const float* nk2 = norm2 + (pair ? (4 + b) : (6 + b)) * 256 + h * 32;
    const float* nq2 = norm2 + (pair ? (2 + b) : (0 + b)) * 256 + h * 32;
    float rs = (pair ? rsy : rsx)[h];
    __shared__ float attn[32][32];
    int t = threadIdx.x;
    if (t < 32) {
        int d = t;
        float nk = fmaxf(sqrtf(nk2[d]), 1e-12f);
        float row[32];
        float mx = -3.4e38f;
#pragma unroll
        for (int e = 0; e < 32; ++e) {
            float nq = fmaxf(sqrtf(nq2[e]), 1e-12f);
            float L = G[d * 32 + e] / (nk * nq) * rs;
            row[e] = L;
            mx = fmaxf(mx, L);
        }
        float sum = 0.f;
#pragma unroll
        for (int e = 0; e < 32; ++e) { row[e] = expf(row[e] - mx); sum += row[e]; }
        float inv = 1.0f / sum;
#pragma unroll
        for (int e = 0; e < 32; ++e) attn[d][e] = row[e] * inv;
    }
    __syncthreads();
    const float* pw = pair ? pyw : pxw;
    int o = t;
    float wrow[32];
#pragma unroll
    for (int d2 = 0; d2 < 32; ++d2) wrow[d2] = pw[o * 256 + h * 32 + d2];
    bf16* dst = PW + ((size_t)(pair * 2 + b) * 256 + o) * 256 + h * 32;
#pragma unroll
    for (int e = 0; e < 32; ++e) {
        float sv = 0.f;
#pragma unroll
        for (int d2 = 0; d2 < 32; ++d2) sv += wrow[d2] * attn[d2][e];
        dst[e] = f2bf(sv);
    }
}

// ======================================================================
// depthwise 3x3 conv, NHWC, zero pad; two streams per dispatch (sel).
// ======================================================================
template<bool GELU_OUT_BF>
__launch_bounds__(256)
__global__ void dwconv_kernel(const bf16* __restrict__ in0, const bf16* __restrict__ in1,
                              const float* __restrict__ wT, const float* __restrict__ bias,
                              bf16* __restrict__ ob0, bf16* __restrict__ ob1,
                              float* __restrict__ of0, float* __restrict__ of1)
{
    int blk = blockIdx.x;
    int sel = blk >> 10;
    const bf16* in = sel ? in1 : in0;
    bf16* outb = sel ? ob1 : ob0;
    float* outf = sel ? of1 : of0;
    int t = (blk & 1023) * 256 + threadIdx.x;
    int cg = t & 31;
    int x = (t >> 5) & 127;
    int chunk = (t >> 12) & 31;
    int b = t >> 17;
    int c0 = cg * 8;

    float w[9][8];
#pragma unroll
    for (int k = 0; k < 9; ++k) {
        float4 a = *(const float4*)(wT + k * 256 + c0);
        float4 bq = *(const float4*)(wT + k * 256 + c0 + 4);
        w[k][0] = a.x; w[k][1] = a.y; w[k][2] = a.z; w[k][3] = a.w;
        w[k][4] = bq.x; w[k][5] = bq.y; w[k][6] = bq.z; w[k][7] = bq.w;
    }
    float bs[8];
    {
        float4 a = *(const float4*)(bias + c0);
        float4 bq = *(const float4*)(bias + c0 + 4);
        bs[0] = a.x; bs[1] = a.y; bs[2] = a.z; bs[3] = a.w;
        bs[4] = bq.x; bs[5] = bq.y; bs[6] = bq.z; bs[7] = bq.w;
    }
    const short8 z = (short8){0, 0, 0, 0, 0, 0, 0, 0};
    bool xm = x > 0, xp = x < 127;
    int y0 = chunk * 4;

    for (int yi = 0; yi < 4; ++yi) {
        int y = y0 + yi;
        float acc[8];
#pragma unroll
        for (int j = 0; j < 8; ++j) acc[j] = bs[j];
#pragma unroll
        for (int ky = -1; ky <= 1; ++ky) {
            int yy = y + ky;
            if (yy < 0 || yy > 127) continue;
            const bf16* rp = in + ((((size_t)b << 14) + (yy << 7) + x) << 8) + c0;
            short8 vm = xm ? *(const short8*)(rp - 256) : z;
            short8 vc = *(const short8*)(rp);
            short8 vp = xp ? *(const short8*)(rp + 256) : z;
            int k0 = (ky + 1) * 3;
#pragma unroll
            for (int j = 0; j < 8; ++j) {
                acc[j] += w[k0 + 0][j] * bfbits2f(vm[j]);
                acc[j] += w[k0 + 1][j] * bfbits2f(vc[j]);
                acc[j] += w[k0 + 2][j] * bfbits2f(vp[j]);
            }
        }
        size_t base = ((((size_t)b << 14) + (y << 7) + x) << 8) + c0;
        if (GELU_OUT_BF) {
            short8 p;
#pragma unroll
            for (int j = 0; j < 8; ++j) {
                float a = acc[j];
                a = 0.5f * a * (1.0f + erff(a * 0.70710678118654752f));
                p[j] = f2bfbits(a);
            }
            *(short8*)(outb + base) = p;
        } else {
            float4* o = (float4*)(outf + base);
            float4 o0 = o[0], o1 = o[1];
            o0.x += acc[0]; o0.y += acc[1]; o0.z += acc[2]; o0.w += acc[3];
            o1.x += acc[4]; o1.y += acc[5]; o1.z += acc[6]; o1.w += acc[7];
            o[0] = o0; o[1] = o1;
        }
    }
}

// ======================================================================
// launch
// ======================================================================
extern "C" void kernel_launch(void* const* d_in, const int* in_sizes, int n_in,
                              void* d_out, int out_size, void* d_ws, size_t ws_size,
                              hipStream_t stream)
{
    const float* x_in  = (const float*)d_in[0];
    const float* y_in  = (const float*)d_in[1];
    const float* fx_w1 = (const float*)d_in[2];
    const float* fx_b1 = (const float*)d_in[3];
    const float* fx_w2 = (const float*)d_in[4];
    const float* fx_b2 = (const float*)d_in[5];
    const float* fy_w1 = (const float*)d_in[6];
    const float* fy_b1 = (const float*)d_in[7];
    const float* fy_w2 = (const float*)d_in[8];
    const float* fy_b2 = (const float*)d_in[9];
    const float* q_w1  = (const float*)d_in[10];
    const float* q_b1  = (const float*)d_in[11];
    const float* q_w2  = (const float*)d_in[12];
    const float* k_w1  = (const float*)d_in[13];
    const float* k_b1  = (const float*)d_in[14];
    const float* k_w2  = (const float*)d_in[15];
    const float* v_w1  = (const float*)d_in[16];
    const float* v_b1  = (const float*)d_in[17];
    const float* v_w2  = (const float*)d_in[18];
    const float* rescale_x = (const float*)d_in[19];
    const float* rescale_y = (const float*)d_in[20];
    const float* px_w  = (const float*)d_in[21];
    const float* px_b  = (const float*)d_in[22];
    const float* py_w  = (const float*)d_in[23];
    const float* py_b  = (const float*)d_in[24];
    const float* pe_w1 = (const float*)d_in[25];
    const float* pe_b1 = (const float*)d_in[26];
    const float* pe_w2 = (const float*)d_in[27];
    const float* pe_b2 = (const float*)d_in[28];

    char* ws = (char*)d_ws;
    const size_t NB = 16777216;
    bf16* xbf  = (bf16*)(ws + 0 * NB);    // [xb | yb] adjacent (65536 rows)
    bf16* ybf  = (bf16*)(ws + 1 * NB);
    bf16* fkx  = (bf16*)(ws + 2 * NB);    // [fkx | fky] adjacent; ctmp after k
    bf16* fky  = (bf16*)(ws + 3 * NB);
    bf16* vbuf = (bf16*)(ws + 4 * NB);    // 65536 rows [vx_b0,vx_b1,vy_b0,vy_b1]
    bf16* qT   = (bf16*)(ws + 6 * NB);    // [256][65536] channel-major
    bf16* kT   = (bf16*)(ws + 8 * NB);
    char* wreg = ws + 10 * NB;
    bf16* w_fx1 = (bf16*)(wreg + 0);
    bf16* w_fx2 = (bf16*)(wreg + 262144);
    bf16* w_fy1 = (bf16*)(wreg + 393216);
    bf16* w_fy2 = (bf16*)(wreg + 655360);
    bf16* w_q1  = (bf16*)(wreg + 786432);
    bf16* w_q2  = (bf16*)(wreg + 917504);
    bf16* w_k1  = (bf16*)(wreg + 1048576);
    bf16* w_k2  = (bf16*)(wreg + 1179648);
    bf16* w_v1  = (bf16*)(wreg + 1310720);
    bf16* w_v2  = (bf16*)(wreg + 1441792);
    float* gram  = (float*)(wreg + 1572864);             // 128 KB
    float* norm2 = (float*)(wreg + 1572864 + 131072);    // 8 KB
    bf16* PW     = (bf16*)(wreg + 1572864 + 139264);     // 512 KB
    float* peT1  = (float*)(wreg + 1572864 + 139264 + 524288);
    float* peT2  = (float*)(wreg + 1572864 + 139264 + 524288 + 9216);
    bf16* ctmp1  = (bf16*)(ws + 2 * NB);
    bf16* ctmp2  = (bf16*)(ws + 3 * NB);

    float* outx = (float*)d_out;
    float* outy = outx + 8388608;

    // ---- prep (casts + transposes + zeroing) ----
    PrepArgs pa;
    pa.x = x_in; pa.y = y_in; pa.xb = xbf; pa.yb = ybf;
    const float* ws_src[10] = {fx_w1, fx_w2, fy_w1, fy_w2, q_w1, q_w2, k_w1, k_w2, v_w1, v_w2};
    bf16* ws_dst[10] = {w_fx1, w_fx2, w_fy1, w_fy2, w_q1, w_q2, w_k1, w_k2, w_v1, w_v2};
    int nblk[10] = {128, 64, 128, 64, 64, 64, 64, 64, 64, 64};
    for (int i = 0; i < 10; ++i) { pa.wsrc[i] = ws_src[i]; pa.wdst[i] = ws_dst[i]; pa.wblk[i] = nblk[i]; }
    pa.pw1 = pe_w1; pa.pw2 = pe_w2; pa.t1 = peT1; pa.t2 = peT2;
    pa.zero = (float4*)gram;
    prep_kernel<<<9012, 256, 0, stream>>>(pa);

    // ---- fused MLPs ----
    MlpArgs fa = {};
    fa.B1[0] = w_fx1; fa.B1[1] = w_fy1; fa.b1[0] = fx_b1; fa.b1[1] = fy_b1;
    fa.W2[0] = w_fx2; fa.W2[1] = w_fy2; fa.b2[0] = fx_b2; fa.b2[1] = fy_b2;
    fa.outb[0] = fkx; fa.outb[1] = fky;
    mlp_kernel<512, true, true, false><<<dim3(2, 256), 512, 0, stream>>>(xbf, ybf, fa);

    MlpArgs qa = {};
    qa.B1[0] = w_q1; qa.B1[1] = w_v1; qa.b1[0] = q_b1; qa.b1[1] = v_b1;
    qa.W2[0] = w_q2; qa.W2[1] = w_v2;
    qa.outT[0] = qT; qa.nrm[0] = norm2;
    qa.outb[1] = vbuf;
    mlp_kernel<256, false, false, true><<<dim3(2, 512), 512, 0, stream>>>(xbf, nullptr, qa);

    MlpArgs ka = {};
    ka.B1[0] = w_k1; ka.b1[0] = k_b1; ka.W2[0] = w_k2;
    ka.outT[0] = kT; ka.nrm[0] = norm2 + 1024;
    mlp_kernel<256, false, false, true><<<dim3(1, 512), 512, 0, stream>>>(fkx, nullptr, ka);

    // ---- pos_emb conv1 (fkx/fky dead now) ----
    dwconv_kernel<true><<<2048, 256, 0, stream>>>(vbuf, vbuf + (size_t)32768 * 256,
                                                  peT1, pe_b1, ctmp1, ctmp2, nullptr, nullptr);

    // ---- attention statistics ----
    gram_mfma_kernel<<<512, 256, 0, stream>>>(qT, kT, gram);
    attn_pw_kernel<<<32, 256, 0, stream>>>(gram, norm2, rescale_x, rescale_y, px_w, py_w, PW);

    // ---- project-out ----
    proj_kernel<<<dim3(1, 512), 512, 0, stream>>>(vbuf, PW, px_b, py_b, outx);

    // ---- pos_emb conv2 (adds into out) ----
    dwconv_kernel<false><<<2048, 256, 0, stream>>>(ctmp1, ctmp2, peT2, pe_b2,
                                                   nullptr, nullptr, outx, outy);
}